// Round 7
// baseline (186.256 us; speedup 1.0000x reference)
//
#include <hip/hip_runtime.h>
#include <hip/hip_bf16.h>

using bf16 = __hip_bfloat16;

#define D_DIM 512
#define C_DIM 2048
#define U_DIM 4
#define DK 64

typedef __attribute__((ext_vector_type(8))) short short8;
typedef __attribute__((ext_vector_type(8))) unsigned short ushort8;
typedef __attribute__((ext_vector_type(4))) float f32x4;

__device__ __forceinline__ float dload(const void* p, size_t i, int f) {
    return f ? ((const float*)p)[i] : __bfloat162float(((const bf16*)p)[i]);
}
__device__ __forceinline__ unsigned f2bf(float x) {
    bf16 b = __float2bfloat16(x);
    return (unsigned)*(unsigned short*)&b;
}
__device__ __forceinline__ float bf2f(unsigned short us) {
    unsigned u = ((unsigned)us) << 16;
    return __builtin_bit_cast(float, u);
}

// ---------------------------------------------------------------------------
// Per-block dtype detect (16 KB of model_embed viewed as bf16; L2-hot).
// ---------------------------------------------------------------------------
__device__ __forceinline__ int block_detect(const void* __restrict__ x) {
    __shared__ int sred[4];
    const bf16* xb = (const bf16*)x;
    int tid = threadIdx.x;
    int cnt = 0;
    #pragma unroll
    for (int i = 0; i < 4; ++i) {
        ushort8 a = *(const ushort8*)(xb + (size_t)(i * 256 + tid) * 8);
        #pragma unroll
        for (int j = 0; j < 8; ++j) {
            float v = fabsf(bf2f(a[j]));
            if (!(v <= 100.0f)) cnt++;
        }
    }
    #pragma unroll
    for (int o = 32; o > 0; o >>= 1) cnt += __shfl_down(cnt, o);
    if ((tid & 63) == 0) sred[tid >> 6] = cnt;
    __syncthreads();
    int c = sred[0] + sred[1] + sred[2] + sred[3];
    return (c > 400) ? 1 : 0;
}

// ---------------------------------------------------------------------------
// A-fragment pack body (dtype compile-time; all loads vectorized).
// ---------------------------------------------------------------------------
template <bool LN, bool XF, bool WF>
__device__ __forceinline__ void pack_a_body(const void* __restrict__ X,
                                            const void* __restrict__ lnw,
                                            const void* __restrict__ lnb,
                                            uint4* __restrict__ Af, int tt) {
    int m = threadIdx.x >> 4;
    int kbL = threadIdx.x & 15;
    int row = tt * 16 + m;
    float v[32];
    float s = 0.0f, ss = 0.0f;
    #pragma unroll
    for (int i = 0; i < 4; ++i) {
        int k0 = (kbL + i * 16) * 8;
        if constexpr (XF) {
            const float4* p = (const float4*)((const float*)X + (size_t)row * D_DIM + k0);
            float4 a = p[0], b = p[1];
            v[i*8+0] = a.x; v[i*8+1] = a.y; v[i*8+2] = a.z; v[i*8+3] = a.w;
            v[i*8+4] = b.x; v[i*8+5] = b.y; v[i*8+6] = b.z; v[i*8+7] = b.w;
        } else {
            ushort8 a = *(const ushort8*)((const bf16*)X + (size_t)row * D_DIM + k0);
            #pragma unroll
            for (int j = 0; j < 8; ++j) v[i*8+j] = bf2f(a[j]);
        }
        #pragma unroll
        for (int j = 0; j < 8; ++j) { float x = v[i*8+j]; s += x; ss += x * x; }
    }
    float mu = 0.0f, rs = 1.0f;
    if (LN) {
        #pragma unroll
        for (int o = 1; o < 16; o <<= 1) { s += __shfl_xor(s, o); ss += __shfl_xor(ss, o); }
        mu = s * (1.0f / D_DIM);
        float var = ss * (1.0f / D_DIM) - mu * mu;
        rs = rsqrtf(var + 1e-5f);
    }
    #pragma unroll
    for (int i = 0; i < 4; ++i) {
        int kb = kbL + i * 16;
        int k0 = kb * 8;
        float lw[8], lb[8];
        if (LN) {
            if constexpr (WF) {
                const float4* pw = (const float4*)((const float*)lnw + k0);
                const float4* pb = (const float4*)((const float*)lnb + k0);
                float4 w0 = pw[0], w1 = pw[1], b0 = pb[0], b1 = pb[1];
                lw[0]=w0.x; lw[1]=w0.y; lw[2]=w0.z; lw[3]=w0.w;
                lw[4]=w1.x; lw[5]=w1.y; lw[6]=w1.z; lw[7]=w1.w;
                lb[0]=b0.x; lb[1]=b0.y; lb[2]=b0.z; lb[3]=b0.w;
                lb[4]=b1.x; lb[5]=b1.y; lb[6]=b1.z; lb[7]=b1.w;
            } else {
                ushort8 w8 = *(const ushort8*)((const bf16*)lnw + k0);
                ushort8 b8 = *(const ushort8*)((const bf16*)lnb + k0);
                #pragma unroll
                for (int j = 0; j < 8; ++j) { lw[j] = bf2f(w8[j]); lb[j] = bf2f(b8[j]); }
            }
        }
        unsigned pk[4];
        #pragma unroll
        for (int jp = 0; jp < 4; ++jp) {
            float v0 = v[i * 8 + jp * 2];
            float v1 = v[i * 8 + jp * 2 + 1];
            if (LN) {
                v0 = (v0 - mu) * rs * lw[jp * 2] + lb[jp * 2];
                v1 = (v1 - mu) * rs * lw[jp * 2 + 1] + lb[jp * 2 + 1];
            }
            pk[jp] = f2bf(v0) | (f2bf(v1) << 16);
        }
        uint4 wv = {pk[0], pk[1], pk[2], pk[3]};
        Af[((size_t)tt * 64 + kb) * 16 + m] = wv;
    }
}

// ---------------------------------------------------------------------------
// Weight pack body (one 64x64 tile into bf16 B-fragments), dtype templated.
// ---------------------------------------------------------------------------
template <bool WF>
__device__ __forceinline__ void pack_w_body(const void* __restrict__ W,
                                            uint4* __restrict__ Bf, int b,
                                            float (*t)[65]) {
    int n0 = (b & 7) * 64, k0 = (b >> 3) * 64;
    int tid = threadIdx.x;
    if constexpr (WF) {
        #pragma unroll
        for (int i = 0; i < 4; ++i) {
            int e = i * 256 + tid;            // vec4 index in [0,1024)
            int r = e >> 4, c = (e & 15) * 4;
            float4 a = *(const float4*)((const float*)W + (size_t)(k0 + r) * D_DIM + n0 + c);
            t[r][c] = a.x; t[r][c+1] = a.y; t[r][c+2] = a.z; t[r][c+3] = a.w;
        }
    } else {
        #pragma unroll
        for (int i = 0; i < 2; ++i) {
            int e = i * 256 + tid;            // vec8 index in [0,512)
            int r = e >> 3, c = (e & 7) * 8;
            ushort8 a = *(const ushort8*)((const bf16*)W + (size_t)(k0 + r) * D_DIM + n0 + c);
            #pragma unroll
            for (int j = 0; j < 8; ++j) t[r][c + j] = bf2f(a[j]);
        }
    }
    __syncthreads();
    #pragma unroll
    for (int i = 0; i < 2; ++i) {
        int e = i * 256 + tid;
        int nl = e & 63, kbl = e >> 6;
        unsigned pk[4];
        #pragma unroll
        for (int jp = 0; jp < 4; ++jp)
            pk[jp] = f2bf(t[kbl * 8 + jp * 2][nl]) | (f2bf(t[kbl * 8 + jp * 2 + 1][nl]) << 16);
        uint4 wv = {pk[0], pk[1], pk[2], pk[3]};
        int n = n0 + nl;
        Bf[(((size_t)(n >> 4)) * 64 + (k0 / 8 + kbl)) * 16 + (n & 15)] = wv;
    }
}

// ---------------------------------------------------------------------------
// FUSED pack: [0,64) me->Aq, [64,576) ck->Ak, [576,704) cv->Av,
// [704,1024) 5 weights -> B-fragments.
// ---------------------------------------------------------------------------
__global__ __launch_bounds__(256, 1)
void pack_all_kernel(const void* __restrict__ me, const void* __restrict__ l1w, const void* __restrict__ l1b,
                     const void* __restrict__ ck, const void* __restrict__ l2w, const void* __restrict__ l2b,
                     const void* __restrict__ cv, const void* __restrict__ l3w, const void* __restrict__ l3b,
                     uint4* __restrict__ Aq, uint4* __restrict__ Ak, uint4* __restrict__ Av,
                     const void* W0, const void* W1, const void* W2,
                     const void* W3, const void* W4,
                     uint4* B0, uint4* B1, uint4* B2, uint4* B3, uint4* B4,
                     int* __restrict__ flagp) {
    __shared__ float t[64][65];
    int f = block_detect(me);
    if (blockIdx.x == 0 && threadIdx.x == 0) *flagp = f;
    int b = blockIdx.x;
    const void* Ws[5] = {W0, W1, W2, W3, W4};
    uint4* Bs[5] = {B0, B1, B2, B3, B4};
    if (f) {
        if (b < 64)       pack_a_body<true, true, true>(me, l1w, l1b, Aq, b);
        else if (b < 576) pack_a_body<true, true, true>(ck, l2w, l2b, Ak, b - 64);
        else if (b < 704) pack_a_body<true, true, true>(cv, l3w, l3b, Av, b - 576);
        else { int c = b - 704; pack_w_body<true>(Ws[c >> 6], Bs[c >> 6], c & 63, t); }
    } else {
        if (b < 64)       pack_a_body<true, false, false>(me, l1w, l1b, Aq, b);
        else if (b < 576) pack_a_body<true, false, false>(ck, l2w, l2b, Ak, b - 64);
        else if (b < 704) pack_a_body<true, false, false>(cv, l3w, l3b, Av, b - 576);
        else { int c = b - 704; pack_w_body<false>(Ws[c >> 6], Bs[c >> 6], c & 63, t); }
    }
}

// ---------------------------------------------------------------------------
// Fragment MFMA GEMM body, templated epilogue:
// OUT=1 score-frag (q); OUT=2 PV B-frag (v); OUT=3 u-split score-B frag (k).
// ---------------------------------------------------------------------------
template <int OUT>
__device__ __forceinline__ void mfma_gemm_body(const uint4* __restrict__ Af,
                                               const uint4* __restrict__ Bf,
                                               const void* __restrict__ bias,
                                               uint4* __restrict__ Fout, int Rtt,
                                               int f, int bx, int by,
                                               float (*t)[65]) {
    int w = threadIdx.x >> 6, lane = threadIdx.x & 63;
    int q = lane >> 4, mn = lane & 15;
    int mt = by * 4 + w;
    int nt0 = bx * 4;
    f32x4 acc[4] = {{0.f,0.f,0.f,0.f},{0.f,0.f,0.f,0.f},{0.f,0.f,0.f,0.f},{0.f,0.f,0.f,0.f}};
    for (int kw = 0; kw < 16; ++kw) {
        short8 a = *(const short8*)(Af + ((size_t)mt * 64 + kw * 4 + q) * 16 + mn);
        #pragma unroll
        for (int i = 0; i < 4; ++i) {
            short8 b = *(const short8*)(Bf + (((size_t)(nt0 + i)) * 64 + kw * 4 + q) * 16 + mn);
            acc[i] = __builtin_amdgcn_mfma_f32_16x16x32_bf16(a, b, acc[i], 0, 0, 0);
        }
    }
    #pragma unroll
    for (int i = 0; i < 4; ++i) {
        float bv = dload(bias, (nt0 + i) * 16 + mn, f);
        #pragma unroll
        for (int r = 0; r < 4; ++r)
            t[w * 16 + q * 4 + r][i * 16 + mn] = acc[i][r] + bv;
    }
    __syncthreads();
    int h = bx;
    if constexpr (OUT == 1) {
        #pragma unroll
        for (int e0 = 0; e0 < 2; ++e0) {
            int e = e0 * 256 + threadIdx.x;
            int m = e & 15, kb = (e >> 4) & 7, ttl = e >> 7;
            const float* src = &t[ttl * 16 + m][kb * 8];
            uint4 wv;
            wv.x = f2bf(src[0]) | (f2bf(src[1]) << 16);
            wv.y = f2bf(src[2]) | (f2bf(src[3]) << 16);
            wv.z = f2bf(src[4]) | (f2bf(src[5]) << 16);
            wv.w = f2bf(src[6]) | (f2bf(src[7]) << 16);
            Fout[(((size_t)h * Rtt + by * 4 + ttl) * 8 + kb) * 16 + m] = wv;
        }
    } else if constexpr (OUT == 2) {
        #pragma unroll
        for (int e0 = 0; e0 < 2; ++e0) {
            int e = e0 * 256 + threadIdx.x;
            int lane2 = e & 63, nt = (e >> 6) & 3, ctl = e >> 8;
            int nm2 = lane2 & 15, q2 = lane2 >> 4;
            int col = nt * 16 + nm2;
            int rb = ctl * 32 + q2 * 8;
            uint4 wv;
            wv.x = f2bf(t[rb + 0][col]) | (f2bf(t[rb + 1][col]) << 16);
            wv.y = f2bf(t[rb + 2][col]) | (f2bf(t[rb + 3][col]) << 16);
            wv.z = f2bf(t[rb + 4][col]) | (f2bf(t[rb + 5][col]) << 16);
            wv.w = f2bf(t[rb + 6][col]) | (f2bf(t[rb + 7][col]) << 16);
            Fout[(((size_t)h * 64 + by * 2 + ctl) * 4 + nt) * 64 + lane2] = wv;
        }
    } else {
        #pragma unroll
        for (int e0 = 0; e0 < 2; ++e0) {
            int e = e0 * 256 + threadIdx.x;
            int m2 = e & 15, kb = (e >> 4) & 7, u = e >> 7;
            const float* src = &t[m2 * 4 + u][kb * 8];
            uint4 wv;
            wv.x = f2bf(src[0]) | (f2bf(src[1]) << 16);
            wv.y = f2bf(src[2]) | (f2bf(src[3]) << 16);
            wv.z = f2bf(src[4]) | (f2bf(src[5]) << 16);
            wv.w = f2bf(src[6]) | (f2bf(src[7]) << 16);
            int nt = by * 4 + u;
            Fout[(((size_t)h * 512 + nt) * 8 + kb) * 16 + m2] = wv;
        }
    }
}

// ---------------------------------------------------------------------------
// FUSED q/k/v projection GEMMs.
// ---------------------------------------------------------------------------
__global__ __launch_bounds__(256, 2)
void gemm_qkv_kernel(const uint4* __restrict__ Aq, const uint4* __restrict__ Ak,
                     const uint4* __restrict__ Av,
                     const uint4* __restrict__ wfq, const uint4* __restrict__ wfk,
                     const uint4* __restrict__ wfv,
                     const void* __restrict__ bq, const void* __restrict__ bk,
                     const void* __restrict__ bv,
                     uint4* __restrict__ qf, uint4* __restrict__ kf,
                     uint4* __restrict__ vf,
                     const int* __restrict__ flagp) {
    __shared__ float t[64][65];
    int f = *flagp;
    int b = blockIdx.x;
    if (b < 1024) {
        mfma_gemm_body<3>(Ak, wfk, bk, kf, 512, f, b >> 7, b & 127, t);
    } else if (b < 1280) {
        int c = b - 1024;
        mfma_gemm_body<2>(Av, wfv, bv, vf, 0, f, c >> 5, c & 31, t);
    } else {
        int c = b - 1280;
        mfma_gemm_body<1>(Aq, wfq, bq, qf, 64, f, c >> 4, c & 15, t);
    }
}

// ---------------------------------------------------------------------------
// FUSED MFMA flash attention v3 — IN-BLOCK c-split merge (unchanged from R5).
// ---------------------------------------------------------------------------
__global__ __launch_bounds__(512, 1)
void attn_fused_kernel(const uint4* __restrict__ qf, const uint4* __restrict__ kf,
                       const uint4* __restrict__ vf, uint4* __restrict__ oAf) {
    __shared__ float sp[8][16][36];      // per-wave P staging (18.4 KB)
    __shared__ float opar[8][16][64];    // per-wave O partials  (32 KB)
    __shared__ float mpar[8][16];        // per-wave row max
    __shared__ float lpar[8][16];        // per-wave row sum
    int tid = threadIdx.x;
    int w = tid >> 6, lane = tid & 63;
    int q = lane >> 4, nm = lane & 15;
    int b = blockIdx.x;
    int h = b & 7;               // XCD selector
    int rt = b >> 3;             // 16-row q tile
    int s = w;                   // wave = c-split chunk

    short8 a0 = *(const short8*)(qf + (((size_t)h * 64 + rt) * 8 + q) * 16 + nm);
    short8 a1 = *(const short8*)(qf + (((size_t)h * 64 + rt) * 8 + 4 + q) * 16 + nm);

    // Phase 1: scores for 8 super-tiles of this wave's chunk, MaxSim over u.
    f32x4 sc[8][2];
    #pragma unroll
    for (int st = 0; st < 8; ++st) {
        #pragma unroll
        for (int hh = 0; hh < 2; ++hh) {
            int ct16 = (s * 8 + st) * 2 + hh;
            f32x4 scv = {-1e30f, -1e30f, -1e30f, -1e30f};
            __builtin_amdgcn_s_setprio(1);
            #pragma unroll
            for (int u = 0; u < 4; ++u) {
                int nt = ct16 * 4 + u;
                short8 b0 = *(const short8*)(kf + (((size_t)h * 512 + nt) * 8 + q) * 16 + nm);
                short8 b1 = *(const short8*)(kf + (((size_t)h * 512 + nt) * 8 + 4 + q) * 16 + nm);
                f32x4 acc = {0.0f, 0.0f, 0.0f, 0.0f};
                acc = __builtin_amdgcn_mfma_f32_16x16x32_bf16(a0, b0, acc, 0, 0, 0);
                acc = __builtin_amdgcn_mfma_f32_16x16x32_bf16(a1, b1, acc, 0, 0, 0);
                #pragma unroll
                for (int r = 0; r < 4; ++r) scv[r] = fmaxf(scv[r], acc[r]);
            }
            __builtin_amdgcn_s_setprio(0);
            #pragma unroll
            for (int r = 0; r < 4; ++r) sc[st][hh][r] = scv[r] * 0.125f;  // 1/sqrt(dk)
        }
    }

    // Phase 2: chunk-local max per query row.
    float mrow[4], lrow[4];
    #pragma unroll
    for (int r = 0; r < 4; ++r) {
        float m = sc[0][0][r];
        #pragma unroll
        for (int st = 0; st < 8; ++st) {
            m = fmaxf(m, sc[st][0][r]);
            m = fmaxf(m, sc[st][1][r]);
        }
        m = fmaxf(m, __shfl_xor(m, 1));
        m = fmaxf(m, __shfl_xor(m, 2));
        m = fmaxf(m, __shfl_xor(m, 4));
        m = fmaxf(m, __shfl_xor(m, 8));
        mrow[r] = m;
        lrow[r] = 0.0f;
    }

    // Phase 3: exp -> P-frag via per-wave LDS -> PV MFMAs.
    f32x4 acc_o[4] = {{0.f,0.f,0.f,0.f},{0.f,0.f,0.f,0.f},{0.f,0.f,0.f,0.f},{0.f,0.f,0.f,0.f}};
    #pragma unroll
    for (int st = 0; st < 8; ++st) {
        #pragma unroll
        for (int r = 0; r < 4; ++r) {
            float p0 = __expf(sc[st][0][r] - mrow[r]);
            float p1 = __expf(sc[st][1][r] - mrow[r]);
            sp[w][q * 4 + r][nm] = p0;
            sp[w][q * 4 + r][16 + nm] = p1;
            lrow[r] += p0 + p1;
        }
        float4 pa0 = *(const float4*)&sp[w][nm][q * 8];
        float4 pa1 = *(const float4*)&sp[w][nm][q * 8 + 4];
        uint4 av;
        av.x = f2bf(pa0.x) | (f2bf(pa0.y) << 16);
        av.y = f2bf(pa0.z) | (f2bf(pa0.w) << 16);
        av.z = f2bf(pa1.x) | (f2bf(pa1.y) << 16);
        av.w = f2bf(pa1.z) | (f2bf(pa1.w) << 16);
        short8 ap = *(short8*)&av;
        int ct32 = s * 8 + st;
        __builtin_amdgcn_s_setprio(1);
        #pragma unroll
        for (int nt2 = 0; nt2 < 4; ++nt2) {
            short8 bv = *(const short8*)(vf + (((size_t)h * 64 + ct32) * 4 + nt2) * 64 + lane);
            acc_o[nt2] = __builtin_amdgcn_mfma_f32_16x16x32_bf16(ap, bv, acc_o[nt2], 0, 0, 0);
        }
        __builtin_amdgcn_s_setprio(0);
    }

    // Chunk-local row-sum reduction.
    #pragma unroll
    for (int r = 0; r < 4; ++r) {
        float ps = lrow[r];
        ps += __shfl_xor(ps, 1);
        ps += __shfl_xor(ps, 2);
        ps += __shfl_xor(ps, 4);
        ps += __shfl_xor(ps, 8);
        lrow[r] = ps;
    }

    // Stage partials to LDS.
    #pragma unroll
    for (int nt2 = 0; nt2 < 4; ++nt2)
        #pragma unroll
        for (int r = 0; r < 4; ++r)
            opar[w][q * 4 + r][nt2 * 16 + nm] = acc_o[nt2][r];
    if (nm == 0) {
        #pragma unroll
        for (int r = 0; r < 4; ++r) {
            mpar[w][q * 4 + r] = mrow[r];
            lpar[w][q * 4 + r] = lrow[r];
        }
    }
    __syncthreads();

    // In-block merge of the 8 c-chunk partials -> wo-GEMM A-frags.
    if (tid < 128) {
        int row = tid & 15, dg = tid >> 4;   // dg in [0,8): 8-col group
        float M = -1e30f;
        #pragma unroll
        for (int ss = 0; ss < 8; ++ss) M = fmaxf(M, mpar[ss][row]);
        float L = 0.0f;
        float o[8] = {0.f,0.f,0.f,0.f,0.f,0.f,0.f,0.f};
        #pragma unroll
        for (int ss = 0; ss < 8; ++ss) {
            float e = __expf(mpar[ss][row] - M);
            L += lpar[ss][row] * e;
            const float* po = &opar[ss][row][dg * 8];
            #pragma unroll
            for (int j = 0; j < 8; ++j) o[j] += po[j] * e;
        }
        float inv = 1.0f / L;
        uint4 u;
        u.x = f2bf(o[0] * inv) | (f2bf(o[1] * inv) << 16);
        u.y = f2bf(o[2] * inv) | (f2bf(o[3] * inv) << 16);
        u.z = f2bf(o[4] * inv) | (f2bf(o[5] * inv) << 16);
        u.w = f2bf(o[6] * inv) | (f2bf(o[7] * inv) << 16);
        int kb = h * 8 + dg;
        oAf[((size_t)rt * 64 + kb) * 16 + row] = u;
    }
}

// ---------------------------------------------------------------------------
// TAIL A: x-quarter = O @ wo + bo (fp32 to global) + per-(rt,quarter) LN4
// partial stats to fixed slots (deterministic, no atomics).
// Grid 256 = 64 rt x 4 col-quarters; 256 threads (4 waves x 2 nt).
// 4x the CU coverage of the old 64-block tail (its 2.5%-occupancy trap).
// ---------------------------------------------------------------------------
__global__ __launch_bounds__(256, 1)
void tailA_kernel(const uint4* __restrict__ oAf, const uint4* __restrict__ wfo,
                  const void* __restrict__ bo,
                  float* __restrict__ xg, float* __restrict__ stats4,
                  const int* __restrict__ flagp) {
    __shared__ float sred[4][16][2];
    int f = *flagp;
    int tid = threadIdx.x;
    int b = blockIdx.x;
    int rt = b >> 2, cq = b & 3;
    int w = tid >> 6, lane = tid & 63;
    int q = lane >> 4, mn = lane & 15;
    int nt0 = cq * 8 + w * 2;

    f32x4 acc[2] = {{0.f,0.f,0.f,0.f},{0.f,0.f,0.f,0.f}};
    for (int kw = 0; kw < 16; ++kw) {
        short8 a = *(const short8*)(oAf + ((size_t)rt * 64 + kw * 4 + q) * 16 + mn);
        #pragma unroll
        for (int i = 0; i < 2; ++i) {
            short8 bb = *(const short8*)(wfo + ((size_t)(nt0 + i) * 64 + kw * 4 + q) * 16 + mn);
            acc[i] = __builtin_amdgcn_mfma_f32_16x16x32_bf16(a, bb, acc[i], 0, 0, 0);
        }
    }
    #pragma unroll
    for (int i = 0; i < 2; ++i) {
        float bv = dload(bo, (nt0 + i) * 16 + mn, f);
        #pragma unroll
        for (int r = 0; r < 4; ++r) acc[i][r] += bv;
    }

    // Write x fp32 (row-major) — full precision for LN in tailB.
    #pragma unroll
    for (int i = 0; i < 2; ++i) {
        int col = (nt0 + i) * 16 + mn;
        #pragma unroll
        for (int r = 0; r < 4; ++r)
            xg[(size_t)(rt * 16 + q * 4 + r) * D_DIM + col] = acc[i][r];
    }

    // Partial LN stats over this quarter's 128 cols.
    {
        float ps[4], pq[4];
        #pragma unroll
        for (int r = 0; r < 4; ++r) {
            float s = acc[0][r] + acc[1][r];
            float sq = acc[0][r] * acc[0][r] + acc[1][r] * acc[1][r];
            #pragma unroll
            for (int o = 1; o < 16; o <<= 1) { s += __shfl_xor(s, o); sq += __shfl_xor(sq, o); }
            ps[r] = s; pq[r] = sq;
        }
        if (mn == 0) {
            #pragma unroll
            for (int r = 0; r < 4; ++r) { sred[w][q*4+r][0] = ps[r]; sred[w][q*4+r][1] = pq[r]; }
        }
    }
    __syncthreads();
    if (tid < 32) {
        int row = tid & 15, which = tid >> 4;
        float v = sred[0][row][which] + sred[1][row][which] +
                  sred[2][row][which] + sred[3][row][which];
        stats4[((size_t)(rt * 16 + row) * 4 + cq) * 2 + which] = v;
    }
}

// ---------------------------------------------------------------------------
// TAIL B: LN4(x) on the fly (fp32 x -> normalize -> bf16 frag) + wp-GEMM
// quarter -> d_out. Grid 256 = 64 rt x 4 col-quarters; fixed-order stat sum.
// ---------------------------------------------------------------------------
__global__ __launch_bounds__(256, 1)
void tailB_kernel(const float* __restrict__ xg, const float* __restrict__ stats4,
                  const uint4* __restrict__ wfp, const void* __restrict__ bp,
                  const void* __restrict__ ln4w, const void* __restrict__ ln4b,
                  float* __restrict__ Y, const int* __restrict__ flagp) {
    __shared__ float lw4[512], lb4[512];
    __shared__ float smu[16], srs[16];
    int f = *flagp;
    int tid = threadIdx.x;
    int b = blockIdx.x;
    int rt = b >> 2, cq = b & 3;
    for (int i = tid; i < 512; i += 256) { lw4[i] = dload(ln4w, i, f); lb4[i] = dload(ln4b, i, f); }
    if (tid < 16) {
        const float* sp4 = stats4 + (size_t)(rt * 16 + tid) * 8;
        float s  = ((sp4[0] + sp4[2]) + sp4[4]) + sp4[6];
        float sq = ((sp4[1] + sp4[3]) + sp4[5]) + sp4[7];
        float mu = s * (1.0f / D_DIM);
        float var = sq * (1.0f / D_DIM) - mu * mu;
        smu[tid] = mu;
        srs[tid] = rsqrtf(var + 1e-5f);
    }
    __syncthreads();

    int w = tid >> 6, lane = tid & 63;
    int q = lane >> 4, mn = lane & 15;
    int nt0 = cq * 8 + w * 2;
    float mu = smu[mn], rs = srs[mn];
    const float* xrow = xg + (size_t)(rt * 16 + mn) * D_DIM;

    f32x4 acc[2] = {{0.f,0.f,0.f,0.f},{0.f,0.f,0.f,0.f}};
    for (int kw = 0; kw < 16; ++kw) {
        int k0 = (kw * 4 + q) * 8;
        float4 x0 = *(const float4*)(xrow + k0);
        float4 x1 = *(const float4*)(xrow + k0 + 4);
        float e[8] = {x0.x, x0.y, x0.z, x0.w, x1.x, x1.y, x1.z, x1.w};
        unsigned pk[4];
        #pragma unroll
        for (int jp = 0; jp < 4; ++jp) {
            float v0 = (e[jp*2]   - mu) * rs * lw4[k0 + jp*2]   + lb4[k0 + jp*2];
            float v1 = (e[jp*2+1] - mu) * rs * lw4[k0 + jp*2+1] + lb4[k0 + jp*2+1];
            pk[jp] = f2bf(v0) | (f2bf(v1) << 16);
        }
        uint4 av = {pk[0], pk[1], pk[2], pk[3]};
        short8 a = *(short8*)&av;
        #pragma unroll
        for (int i = 0; i < 2; ++i) {
            short8 bb = *(const short8*)(wfp + ((size_t)(nt0 + i) * 64 + kw * 4 + q) * 16 + mn);
            acc[i] = __builtin_amdgcn_mfma_f32_16x16x32_bf16(a, bb, acc[i], 0, 0, 0);
        }
    }
    #pragma unroll
    for (int i = 0; i < 2; ++i) {
        int col = (nt0 + i) * 16 + mn;
        float bv = dload(bp, col, f);
        #pragma unroll
        for (int r = 0; r < 4; ++r)
            Y[(size_t)(rt * 16 + q * 4 + r) * D_DIM + col] = acc[i][r] + bv;
    }
}

extern "C" void kernel_launch(void* const* d_in, const int* in_sizes, int n_in,
                              void* d_out, int out_size, void* d_ws, size_t ws_size,
                              hipStream_t stream) {
    const void* model_embed = d_in[0];
    const void* ctx_key     = d_in[1];
    const void* ctx_val     = d_in[2];
    const void* ln1w = d_in[3];  const void* ln1b = d_in[4];
    const void* ln2w = d_in[5];  const void* ln2b = d_in[6];
    const void* ln3w = d_in[7];  const void* ln3b = d_in[8];
    const void* ln4w = d_in[9];  const void* ln4b = d_in[10];
    const void* wq = d_in[11];   const void* bq = d_in[12];
    const void* wk = d_in[13];   const void* bk = d_in[14];
    const void* wv = d_in[15];   const void* bv = d_in[16];
    const void* wo = d_in[17];   const void* bo = d_in[18];
    const void* wp = d_in[19];   const void* bp = d_in[20];

    int*   flagp = (int*)d_ws;
    float* ws    = (float*)d_ws + 16;
    float* o1    = ws;                         // 524288 fl (oAf lives here)
    float* qTf   = o1 + 524288;                // qf   262144 fl (1 MB)
    float* kTf   = qTf + 262144;               // kf  2097152 fl (8 MB)
    float* Aqf   = kTf + 2097152;              // Aq   262144 fl
    float* Akf   = Aqf + 262144;               // Ak  2097152 fl
    float* Avf   = Akf + 2097152;              // Av   524288 fl
    float* vff   = Avf + 524288;               // vf   524288 fl
    float* wfr   = vff + 524288;               // 655360 fl (5 W-frags)
    float* xg    = wfr + 655360;               // 524288 fl (2 MB fp32 x)
    float* st4   = xg + 524288;                // 8192 fl (LN4 partial stats)

    uint4* qf  = (uint4*)qTf;
    uint4* kf  = (uint4*)kTf;
    uint4* Aq  = (uint4*)Aqf;
    uint4* Ak  = (uint4*)Akf;
    uint4* Av  = (uint4*)Avf;
    uint4* vf  = (uint4*)vff;
    uint4* oAf = (uint4*)o1;
    uint4* wfq = (uint4*)wfr;
    uint4* wfk = wfq + 32768;
    uint4* wfv = wfk + 32768;
    uint4* wfo = wfv + 32768;
    uint4* wfp = wfo + 32768;

    pack_all_kernel<<<1024, 256, 0, stream>>>(model_embed, ln1w, ln1b,
                                              ctx_key, ln2w, ln2b,
                                              ctx_val, ln3w, ln3b,
                                              Aq, Ak, Av,
                                              wq, wk, wv, wo, wp,
                                              wfq, wfk, wfv, wfo, wfp, flagp);

    gemm_qkv_kernel<<<1408, 256, 0, stream>>>(Aq, Ak, Av, wfq, wfk, wfv,
                                              bq, bk, bv, qf, kf, vf, flagp);

    attn_fused_kernel<<<512, 512, 0, stream>>>(qf, kf, vf, oAf);

    tailA_kernel<<<256, 256, 0, stream>>>(oAf, wfo, bo, xg, st4, flagp);

    tailB_kernel<<<256, 256, 0, stream>>>(xg, st4, wfp, bp, ln4w, ln4b,
                                          (float*)d_out, flagp);

    (void)ws_size;
}

// Round 8
// 175.624 us; speedup vs baseline: 1.0605x; 1.0605x over previous
//
#include <hip/hip_runtime.h>
#include <hip/hip_bf16.h>

using bf16 = __hip_bfloat16;

#define D_DIM 512
#define C_DIM 2048
#define U_DIM 4
#define DK 64

typedef __attribute__((ext_vector_type(8))) short short8;
typedef __attribute__((ext_vector_type(8))) unsigned short ushort8;
typedef __attribute__((ext_vector_type(4))) float f32x4;

__device__ __forceinline__ float dload(const void* p, size_t i, int f) {
    return f ? ((const float*)p)[i] : __bfloat162float(((const bf16*)p)[i]);
}
__device__ __forceinline__ unsigned f2bf(float x) {
    bf16 b = __float2bfloat16(x);
    return (unsigned)*(unsigned short*)&b;
}
__device__ __forceinline__ float bf2f(unsigned short us) {
    unsigned u = ((unsigned)us) << 16;
    return __builtin_bit_cast(float, u);
}

// ---------------------------------------------------------------------------
// Per-block dtype detect (16 KB of model_embed viewed as bf16; L2-hot).
// ---------------------------------------------------------------------------
__device__ __forceinline__ int block_detect(const void* __restrict__ x) {
    __shared__ int sred[4];
    const bf16* xb = (const bf16*)x;
    int tid = threadIdx.x;
    int cnt = 0;
    #pragma unroll
    for (int i = 0; i < 4; ++i) {
        ushort8 a = *(const ushort8*)(xb + (size_t)(i * 256 + tid) * 8);
        #pragma unroll
        for (int j = 0; j < 8; ++j) {
            float v = fabsf(bf2f(a[j]));
            if (!(v <= 100.0f)) cnt++;
        }
    }
    #pragma unroll
    for (int o = 32; o > 0; o >>= 1) cnt += __shfl_down(cnt, o);
    if ((tid & 63) == 0) sred[tid >> 6] = cnt;
    __syncthreads();
    int c = sred[0] + sred[1] + sred[2] + sred[3];
    return (c > 400) ? 1 : 0;
}

// ---------------------------------------------------------------------------
// A-fragment pack body (dtype compile-time; all loads vectorized).
// ---------------------------------------------------------------------------
template <bool LN, bool XF, bool WF>
__device__ __forceinline__ void pack_a_body(const void* __restrict__ X,
                                            const void* __restrict__ lnw,
                                            const void* __restrict__ lnb,
                                            uint4* __restrict__ Af, int tt) {
    int m = threadIdx.x >> 4;
    int kbL = threadIdx.x & 15;
    int row = tt * 16 + m;
    float v[32];
    float s = 0.0f, ss = 0.0f;
    #pragma unroll
    for (int i = 0; i < 4; ++i) {
        int k0 = (kbL + i * 16) * 8;
        if constexpr (XF) {
            const float4* p = (const float4*)((const float*)X + (size_t)row * D_DIM + k0);
            float4 a = p[0], b = p[1];
            v[i*8+0] = a.x; v[i*8+1] = a.y; v[i*8+2] = a.z; v[i*8+3] = a.w;
            v[i*8+4] = b.x; v[i*8+5] = b.y; v[i*8+6] = b.z; v[i*8+7] = b.w;
        } else {
            ushort8 a = *(const ushort8*)((const bf16*)X + (size_t)row * D_DIM + k0);
            #pragma unroll
            for (int j = 0; j < 8; ++j) v[i*8+j] = bf2f(a[j]);
        }
        #pragma unroll
        for (int j = 0; j < 8; ++j) { float x = v[i*8+j]; s += x; ss += x * x; }
    }
    float mu = 0.0f, rs = 1.0f;
    if (LN) {
        #pragma unroll
        for (int o = 1; o < 16; o <<= 1) { s += __shfl_xor(s, o); ss += __shfl_xor(ss, o); }
        mu = s * (1.0f / D_DIM);
        float var = ss * (1.0f / D_DIM) - mu * mu;
        rs = rsqrtf(var + 1e-5f);
    }
    #pragma unroll
    for (int i = 0; i < 4; ++i) {
        int kb = kbL + i * 16;
        int k0 = kb * 8;
        float lw[8], lb[8];
        if (LN) {
            if constexpr (WF) {
                const float4* pw = (const float4*)((const float*)lnw + k0);
                const float4* pb = (const float4*)((const float*)lnb + k0);
                float4 w0 = pw[0], w1 = pw[1], b0 = pb[0], b1 = pb[1];
                lw[0]=w0.x; lw[1]=w0.y; lw[2]=w0.z; lw[3]=w0.w;
                lw[4]=w1.x; lw[5]=w1.y; lw[6]=w1.z; lw[7]=w1.w;
                lb[0]=b0.x; lb[1]=b0.y; lb[2]=b0.z; lb[3]=b0.w;
                lb[4]=b1.x; lb[5]=b1.y; lb[6]=b1.z; lb[7]=b1.w;
            } else {
                ushort8 w8 = *(const ushort8*)((const bf16*)lnw + k0);
                ushort8 b8 = *(const ushort8*)((const bf16*)lnb + k0);
                #pragma unroll
                for (int j = 0; j < 8; ++j) { lw[j] = bf2f(w8[j]); lb[j] = bf2f(b8[j]); }
            }
        }
        unsigned pk[4];
        #pragma unroll
        for (int jp = 0; jp < 4; ++jp) {
            float v0 = v[i * 8 + jp * 2];
            float v1 = v[i * 8 + jp * 2 + 1];
            if (LN) {
                v0 = (v0 - mu) * rs * lw[jp * 2] + lb[jp * 2];
                v1 = (v1 - mu) * rs * lw[jp * 2 + 1] + lb[jp * 2 + 1];
            }
            pk[jp] = f2bf(v0) | (f2bf(v1) << 16);
        }
        uint4 wv = {pk[0], pk[1], pk[2], pk[3]};
        Af[((size_t)tt * 64 + kb) * 16 + m] = wv;
    }
}

// ---------------------------------------------------------------------------
// Weight pack body (one 64x64 tile into bf16 B-fragments), dtype templated.
// ---------------------------------------------------------------------------
template <bool WF>
__device__ __forceinline__ void pack_w_body(const void* __restrict__ W,
                                            uint4* __restrict__ Bf, int b,
                                            float (*t)[65]) {
    int n0 = (b & 7) * 64, k0 = (b >> 3) * 64;
    int tid = threadIdx.x;
    if constexpr (WF) {
        #pragma unroll
        for (int i = 0; i < 4; ++i) {
            int e = i * 256 + tid;            // vec4 index in [0,1024)
            int r = e >> 4, c = (e & 15) * 4;
            float4 a = *(const float4*)((const float*)W + (size_t)(k0 + r) * D_DIM + n0 + c);
            t[r][c] = a.x; t[r][c+1] = a.y; t[r][c+2] = a.z; t[r][c+3] = a.w;
        }
    } else {
        #pragma unroll
        for (int i = 0; i < 2; ++i) {
            int e = i * 256 + tid;            // vec8 index in [0,512)
            int r = e >> 3, c = (e & 7) * 8;
            ushort8 a = *(const ushort8*)((const bf16*)W + (size_t)(k0 + r) * D_DIM + n0 + c);
            #pragma unroll
            for (int j = 0; j < 8; ++j) t[r][c + j] = bf2f(a[j]);
        }
    }
    __syncthreads();
    #pragma unroll
    for (int i = 0; i < 2; ++i) {
        int e = i * 256 + tid;
        int nl = e & 63, kbl = e >> 6;
        unsigned pk[4];
        #pragma unroll
        for (int jp = 0; jp < 4; ++jp)
            pk[jp] = f2bf(t[kbl * 8 + jp * 2][nl]) | (f2bf(t[kbl * 8 + jp * 2 + 1][nl]) << 16);
        uint4 wv = {pk[0], pk[1], pk[2], pk[3]};
        int n = n0 + nl;
        Bf[(((size_t)(n >> 4)) * 64 + (k0 / 8 + kbl)) * 16 + (n & 15)] = wv;
    }
}

// ---------------------------------------------------------------------------
// FUSED pack: [0,64) me->Aq, [64,576) ck->Ak, [576,704) cv->Av,
// [704,1024) 5 weights -> B-fragments.
// ---------------------------------------------------------------------------
__global__ __launch_bounds__(256, 1)
void pack_all_kernel(const void* __restrict__ me, const void* __restrict__ l1w, const void* __restrict__ l1b,
                     const void* __restrict__ ck, const void* __restrict__ l2w, const void* __restrict__ l2b,
                     const void* __restrict__ cv, const void* __restrict__ l3w, const void* __restrict__ l3b,
                     uint4* __restrict__ Aq, uint4* __restrict__ Ak, uint4* __restrict__ Av,
                     const void* W0, const void* W1, const void* W2,
                     const void* W3, const void* W4,
                     uint4* B0, uint4* B1, uint4* B2, uint4* B3, uint4* B4,
                     int* __restrict__ flagp) {
    __shared__ float t[64][65];
    int f = block_detect(me);
    if (blockIdx.x == 0 && threadIdx.x == 0) *flagp = f;
    int b = blockIdx.x;
    const void* Ws[5] = {W0, W1, W2, W3, W4};
    uint4* Bs[5] = {B0, B1, B2, B3, B4};
    if (f) {
        if (b < 64)       pack_a_body<true, true, true>(me, l1w, l1b, Aq, b);
        else if (b < 576) pack_a_body<true, true, true>(ck, l2w, l2b, Ak, b - 64);
        else if (b < 704) pack_a_body<true, true, true>(cv, l3w, l3b, Av, b - 576);
        else { int c = b - 704; pack_w_body<true>(Ws[c >> 6], Bs[c >> 6], c & 63, t); }
    } else {
        if (b < 64)       pack_a_body<true, false, false>(me, l1w, l1b, Aq, b);
        else if (b < 576) pack_a_body<true, false, false>(ck, l2w, l2b, Ak, b - 64);
        else if (b < 704) pack_a_body<true, false, false>(cv, l3w, l3b, Av, b - 576);
        else { int c = b - 704; pack_w_body<false>(Ws[c >> 6], Bs[c >> 6], c & 63, t); }
    }
}

// ---------------------------------------------------------------------------
// Fragment MFMA GEMM body with B-tile LDS DOUBLE-BUFFER (T3-lite):
// all 4 waves of a block consume the IDENTICAL B stream, so one cooperative
// 16 KB stage per kw-quarter replaces 4x redundant per-MFMA L2 loads; the
// stage loads issue BEFORE the MFMA cluster (write-late pattern, R4).
// Epilogues: OUT=1 score-frag (q); OUT=2 PV B-frag (v); OUT=3 u-split (k).
// ---------------------------------------------------------------------------
template <int OUT>
__device__ __forceinline__ void mfma_gemm_body(const uint4* __restrict__ Af,
                                               const uint4* __restrict__ Bf,
                                               const void* __restrict__ bias,
                                               uint4* __restrict__ Fout, int Rtt,
                                               int f, int bx, int by,
                                               float (*t)[65],
                                               uint4 (*bbuf)[1024]) {
    int tid = threadIdx.x;
    int w = tid >> 6, lane = tid & 63;
    int q = lane >> 4, mn = lane & 15;
    int mt = by * 4 + w;
    int nt0 = bx * 4;

    // Prologue: stage kw-quarter 0 (kw 0..3) into bbuf[0].
    uint4 stg[4];
    #pragma unroll
    for (int j = 0; j < 4; ++j) {
        int e = j * 256 + tid;
        int emn = e & 15, rest = e >> 4, i = rest & 3, kq = rest >> 2;
        stg[j] = Bf[(((size_t)(nt0 + i)) * 64 + kq) * 16 + emn];
    }
    #pragma unroll
    for (int j = 0; j < 4; ++j) bbuf[0][j * 256 + tid] = stg[j];
    __syncthreads();

    f32x4 acc[4] = {{0.f,0.f,0.f,0.f},{0.f,0.f,0.f,0.f},{0.f,0.f,0.f,0.f},{0.f,0.f,0.f,0.f}};
    #pragma unroll
    for (int p = 0; p < 4; ++p) {
        const int cur = p & 1;
        if (p < 3) {   // issue next-quarter loads early (latency under MFMAs)
            #pragma unroll
            for (int j = 0; j < 4; ++j) {
                int e = j * 256 + tid;
                int emn = e & 15, rest = e >> 4, i = rest & 3, kq = rest >> 2;
                stg[j] = Bf[(((size_t)(nt0 + i)) * 64 + (p + 1) * 16 + kq) * 16 + emn];
            }
        }
        #pragma unroll
        for (int kwl = 0; kwl < 4; ++kwl) {
            int kw = p * 4 + kwl;
            short8 a = *(const short8*)(Af + ((size_t)mt * 64 + kw * 4 + q) * 16 + mn);
            #pragma unroll
            for (int i = 0; i < 4; ++i) {
                short8 b = *(const short8*)&bbuf[cur][((kwl * 4 + q) * 4 + i) * 16 + mn];
                acc[i] = __builtin_amdgcn_mfma_f32_16x16x32_bf16(a, b, acc[i], 0, 0, 0);
            }
        }
        if (p < 3) {   // write-late into the other buffer, then barrier
            #pragma unroll
            for (int j = 0; j < 4; ++j) bbuf[cur ^ 1][j * 256 + tid] = stg[j];
            __syncthreads();
        }
    }

    #pragma unroll
    for (int i = 0; i < 4; ++i) {
        float bv = dload(bias, (nt0 + i) * 16 + mn, f);
        #pragma unroll
        for (int r = 0; r < 4; ++r)
            t[w * 16 + q * 4 + r][i * 16 + mn] = acc[i][r] + bv;
    }
    __syncthreads();
    int h = bx;
    if constexpr (OUT == 1) {
        #pragma unroll
        for (int e0 = 0; e0 < 2; ++e0) {
            int e = e0 * 256 + threadIdx.x;
            int m = e & 15, kb = (e >> 4) & 7, ttl = e >> 7;
            const float* src = &t[ttl * 16 + m][kb * 8];
            uint4 wv;
            wv.x = f2bf(src[0]) | (f2bf(src[1]) << 16);
            wv.y = f2bf(src[2]) | (f2bf(src[3]) << 16);
            wv.z = f2bf(src[4]) | (f2bf(src[5]) << 16);
            wv.w = f2bf(src[6]) | (f2bf(src[7]) << 16);
            Fout[(((size_t)h * Rtt + by * 4 + ttl) * 8 + kb) * 16 + m] = wv;
        }
    } else if constexpr (OUT == 2) {
        #pragma unroll
        for (int e0 = 0; e0 < 2; ++e0) {
            int e = e0 * 256 + threadIdx.x;
            int lane2 = e & 63, nt = (e >> 6) & 3, ctl = e >> 8;
            int nm2 = lane2 & 15, q2 = lane2 >> 4;
            int col = nt * 16 + nm2;
            int rb = ctl * 32 + q2 * 8;
            uint4 wv;
            wv.x = f2bf(t[rb + 0][col]) | (f2bf(t[rb + 1][col]) << 16);
            wv.y = f2bf(t[rb + 2][col]) | (f2bf(t[rb + 3][col]) << 16);
            wv.z = f2bf(t[rb + 4][col]) | (f2bf(t[rb + 5][col]) << 16);
            wv.w = f2bf(t[rb + 6][col]) | (f2bf(t[rb + 7][col]) << 16);
            Fout[(((size_t)h * 64 + by * 2 + ctl) * 4 + nt) * 64 + lane2] = wv;
        }
    } else {
        #pragma unroll
        for (int e0 = 0; e0 < 2; ++e0) {
            int e = e0 * 256 + threadIdx.x;
            int m2 = e & 15, kb = (e >> 4) & 7, u = e >> 7;
            const float* src = &t[m2 * 4 + u][kb * 8];
            uint4 wv;
            wv.x = f2bf(src[0]) | (f2bf(src[1]) << 16);
            wv.y = f2bf(src[2]) | (f2bf(src[3]) << 16);
            wv.z = f2bf(src[4]) | (f2bf(src[5]) << 16);
            wv.w = f2bf(src[6]) | (f2bf(src[7]) << 16);
            int nt = by * 4 + u;
            Fout[(((size_t)h * 512 + nt) * 8 + kb) * 16 + m2] = wv;
        }
    }
}

// ---------------------------------------------------------------------------
// FUSED q/k/v projection GEMMs (with B LDS double-buffer).
// ---------------------------------------------------------------------------
__global__ __launch_bounds__(256, 2)
void gemm_qkv_kernel(const uint4* __restrict__ Aq, const uint4* __restrict__ Ak,
                     const uint4* __restrict__ Av,
                     const uint4* __restrict__ wfq, const uint4* __restrict__ wfk,
                     const uint4* __restrict__ wfv,
                     const void* __restrict__ bq, const void* __restrict__ bk,
                     const void* __restrict__ bv,
                     uint4* __restrict__ qf, uint4* __restrict__ kf,
                     uint4* __restrict__ vf,
                     const int* __restrict__ flagp) {
    __shared__ float t[64][65];
    __shared__ uint4 bbuf[2][1024];      // 2 x 16 KB B-quarter double-buffer
    int f = *flagp;
    int b = blockIdx.x;
    if (b < 1024) {
        mfma_gemm_body<3>(Ak, wfk, bk, kf, 512, f, b >> 7, b & 127, t, bbuf);
    } else if (b < 1280) {
        int c = b - 1024;
        mfma_gemm_body<2>(Av, wfv, bv, vf, 0, f, c >> 5, c & 31, t, bbuf);
    } else {
        int c = b - 1280;
        mfma_gemm_body<1>(Aq, wfq, bq, qf, 64, f, c >> 4, c & 15, t, bbuf);
    }
}

// ---------------------------------------------------------------------------
// FUSED MFMA flash attention v3 — IN-BLOCK c-split merge (R5, best measured).
// ---------------------------------------------------------------------------
__global__ __launch_bounds__(512, 1)
void attn_fused_kernel(const uint4* __restrict__ qf, const uint4* __restrict__ kf,
                       const uint4* __restrict__ vf, uint4* __restrict__ oAf) {
    __shared__ float sp[8][16][36];      // per-wave P staging (18.4 KB)
    __shared__ float opar[8][16][64];    // per-wave O partials  (32 KB)
    __shared__ float mpar[8][16];        // per-wave row max
    __shared__ float lpar[8][16];        // per-wave row sum
    int tid = threadIdx.x;
    int w = tid >> 6, lane = tid & 63;
    int q = lane >> 4, nm = lane & 15;
    int b = blockIdx.x;
    int h = b & 7;               // XCD selector
    int rt = b >> 3;             // 16-row q tile
    int s = w;                   // wave = c-split chunk

    short8 a0 = *(const short8*)(qf + (((size_t)h * 64 + rt) * 8 + q) * 16 + nm);
    short8 a1 = *(const short8*)(qf + (((size_t)h * 64 + rt) * 8 + 4 + q) * 16 + nm);

    // Phase 1: scores for 8 super-tiles of this wave's chunk, MaxSim over u.
    f32x4 sc[8][2];
    #pragma unroll
    for (int st = 0; st < 8; ++st) {
        #pragma unroll
        for (int hh = 0; hh < 2; ++hh) {
            int ct16 = (s * 8 + st) * 2 + hh;
            f32x4 scv = {-1e30f, -1e30f, -1e30f, -1e30f};
            __builtin_amdgcn_s_setprio(1);
            #pragma unroll
            for (int u = 0; u < 4; ++u) {
                int nt = ct16 * 4 + u;
                short8 b0 = *(const short8*)(kf + (((size_t)h * 512 + nt) * 8 + q) * 16 + nm);
                short8 b1 = *(const short8*)(kf + (((size_t)h * 512 + nt) * 8 + 4 + q) * 16 + nm);
                f32x4 acc = {0.0f, 0.0f, 0.0f, 0.0f};
                acc = __builtin_amdgcn_mfma_f32_16x16x32_bf16(a0, b0, acc, 0, 0, 0);
                acc = __builtin_amdgcn_mfma_f32_16x16x32_bf16(a1, b1, acc, 0, 0, 0);
                #pragma unroll
                for (int r = 0; r < 4; ++r) scv[r] = fmaxf(scv[r], acc[r]);
            }
            __builtin_amdgcn_s_setprio(0);
            #pragma unroll
            for (int r = 0; r < 4; ++r) sc[st][hh][r] = scv[r] * 0.125f;  // 1/sqrt(dk)
        }
    }

    // Phase 2: chunk-local max per query row.
    float mrow[4], lrow[4];
    #pragma unroll
    for (int r = 0; r < 4; ++r) {
        float m = sc[0][0][r];
        #pragma unroll
        for (int st = 0; st < 8; ++st) {
            m = fmaxf(m, sc[st][0][r]);
            m = fmaxf(m, sc[st][1][r]);
        }
        m = fmaxf(m, __shfl_xor(m, 1));
        m = fmaxf(m, __shfl_xor(m, 2));
        m = fmaxf(m, __shfl_xor(m, 4));
        m = fmaxf(m, __shfl_xor(m, 8));
        mrow[r] = m;
        lrow[r] = 0.0f;
    }

    // Phase 3: exp -> P-frag via per-wave LDS -> PV MFMAs.
    f32x4 acc_o[4] = {{0.f,0.f,0.f,0.f},{0.f,0.f,0.f,0.f},{0.f,0.f,0.f,0.f},{0.f,0.f,0.f,0.f}};
    #pragma unroll
    for (int st = 0; st < 8; ++st) {
        #pragma unroll
        for (int r = 0; r < 4; ++r) {
            float p0 = __expf(sc[st][0][r] - mrow[r]);
            float p1 = __expf(sc[st][1][r] - mrow[r]);
            sp[w][q * 4 + r][nm] = p0;
            sp[w][q * 4 + r][16 + nm] = p1;
            lrow[r] += p0 + p1;
        }
        float4 pa0 = *(const float4*)&sp[w][nm][q * 8];
        float4 pa1 = *(const float4*)&sp[w][nm][q * 8 + 4];
        uint4 av;
        av.x = f2bf(pa0.x) | (f2bf(pa0.y) << 16);
        av.y = f2bf(pa0.z) | (f2bf(pa0.w) << 16);
        av.z = f2bf(pa1.x) | (f2bf(pa1.y) << 16);
        av.w = f2bf(pa1.z) | (f2bf(pa1.w) << 16);
        short8 ap = *(short8*)&av;
        int ct32 = s * 8 + st;
        __builtin_amdgcn_s_setprio(1);
        #pragma unroll
        for (int nt2 = 0; nt2 < 4; ++nt2) {
            short8 bv = *(const short8*)(vf + (((size_t)h * 64 + ct32) * 4 + nt2) * 64 + lane);
            acc_o[nt2] = __builtin_amdgcn_mfma_f32_16x16x32_bf16(ap, bv, acc_o[nt2], 0, 0, 0);
        }
        __builtin_amdgcn_s_setprio(0);
    }

    // Chunk-local row-sum reduction.
    #pragma unroll
    for (int r = 0; r < 4; ++r) {
        float ps = lrow[r];
        ps += __shfl_xor(ps, 1);
        ps += __shfl_xor(ps, 2);
        ps += __shfl_xor(ps, 4);
        ps += __shfl_xor(ps, 8);
        lrow[r] = ps;
    }

    // Stage partials to LDS.
    #pragma unroll
    for (int nt2 = 0; nt2 < 4; ++nt2)
        #pragma unroll
        for (int r = 0; r < 4; ++r)
            opar[w][q * 4 + r][nt2 * 16 + nm] = acc_o[nt2][r];
    if (nm == 0) {
        #pragma unroll
        for (int r = 0; r < 4; ++r) {
            mpar[w][q * 4 + r] = mrow[r];
            lpar[w][q * 4 + r] = lrow[r];
        }
    }
    __syncthreads();

    // In-block merge of the 8 c-chunk partials -> wo-GEMM A-frags.
    if (tid < 128) {
        int row = tid & 15, dg = tid >> 4;   // dg in [0,8): 8-col group
        float M = -1e30f;
        #pragma unroll
        for (int ss = 0; ss < 8; ++ss) M = fmaxf(M, mpar[ss][row]);
        float L = 0.0f;
        float o[8] = {0.f,0.f,0.f,0.f,0.f,0.f,0.f,0.f};
        #pragma unroll
        for (int ss = 0; ss < 8; ++ss) {
            float e = __expf(mpar[ss][row] - M);
            L += lpar[ss][row] * e;
            const float* po = &opar[ss][row][dg * 8];
            #pragma unroll
            for (int j = 0; j < 8; ++j) o[j] += po[j] * e;
        }
        float inv = 1.0f / L;
        uint4 u;
        u.x = f2bf(o[0] * inv) | (f2bf(o[1] * inv) << 16);
        u.y = f2bf(o[2] * inv) | (f2bf(o[3] * inv) << 16);
        u.z = f2bf(o[4] * inv) | (f2bf(o[5] * inv) << 16);
        u.w = f2bf(o[6] * inv) | (f2bf(o[7] * inv) << 16);
        int kb = h * 8 + dg;
        oAf[((size_t)rt * 64 + kb) * 16 + row] = u;
    }
}

// ---------------------------------------------------------------------------
// FUSED TAIL v2 (R5 form — best measured): wo-GEMM -> LN4 -> wp-GEMM.
// 64 blocks x 512 threads.
// ---------------------------------------------------------------------------
__global__ __launch_bounds__(512, 1)
void tail2_kernel(const uint4* __restrict__ oAf,
                  const uint4* __restrict__ wfo, const uint4* __restrict__ wfp,
                  const void* __restrict__ bo, const void* __restrict__ bp,
                  const void* __restrict__ ln4w, const void* __restrict__ ln4b,
                  float* __restrict__ Y, const int* __restrict__ flagp) {
    __shared__ uint4 lfr[64][16];          // LN4(x) A-frags (16 KB)
    __shared__ float xs[8][16][68];        // per-wave fp32 x staging (34.8 KB)
    __shared__ float lw4[512], lb4[512];   // ln4 params (4 KB)
    __shared__ float sred[8][16][2];       // per-wave row (sum, sumsq) (1 KB)
    int f = *flagp;
    int tid = threadIdx.x;
    int rt = blockIdx.x;                   // rows rt*16 .. rt*16+16
    if (tid < 512) { lw4[tid] = dload(ln4w, tid, f); lb4[tid] = dload(ln4b, tid, f); }

    int w = tid >> 6, lane = tid & 63;
    int q = lane >> 4, mn = lane & 15;

    // ---- G1: x = O @ wo + bo; wave w -> nt = w*4+i ----
    f32x4 acc[4] = {{0.f,0.f,0.f,0.f},{0.f,0.f,0.f,0.f},{0.f,0.f,0.f,0.f},{0.f,0.f,0.f,0.f}};
    for (int kw = 0; kw < 16; ++kw) {
        short8 a = *(const short8*)(oAf + ((size_t)rt * 64 + kw * 4 + q) * 16 + mn);
        #pragma unroll
        for (int i = 0; i < 4; ++i) {
            int nt = w * 4 + i;
            short8 b = *(const short8*)(wfo + ((size_t)nt * 64 + kw * 4 + q) * 16 + mn);
            acc[i] = __builtin_amdgcn_mfma_f32_16x16x32_bf16(a, b, acc[i], 0, 0, 0);
        }
    }
    #pragma unroll
    for (int i = 0; i < 4; ++i) {
        float bv = dload(bo, (w * 4 + i) * 16 + mn, f);
        #pragma unroll
        for (int r = 0; r < 4; ++r) acc[i][r] += bv;
    }

    // ---- LN4 stats: in-lane over 4 nt, shfl over 16 mn, LDS over 8 waves ----
    {
        float ps[4], pq[4];
        #pragma unroll
        for (int r = 0; r < 4; ++r) {
            float s = 0.f, sq = 0.f;
            #pragma unroll
            for (int i = 0; i < 4; ++i) { float x = acc[i][r]; s += x; sq += x * x; }
            #pragma unroll
            for (int o = 1; o < 16; o <<= 1) { s += __shfl_xor(s, o); sq += __shfl_xor(sq, o); }
            ps[r] = s; pq[r] = sq;
        }
        if (mn == 0) {
            #pragma unroll
            for (int r = 0; r < 4; ++r) { sred[w][q*4+r][0] = ps[r]; sred[w][q*4+r][1] = pq[r]; }
        }
    }
    __syncthreads();

    float mu[4], rs[4];
    #pragma unroll
    for (int r = 0; r < 4; ++r) {
        int rr = q * 4 + r;
        float s = 0.f, sq = 0.f;
        #pragma unroll
        for (int ww = 0; ww < 8; ++ww) { s += sred[ww][rr][0]; sq += sred[ww][rr][1]; }
        mu[r] = s * (1.0f / D_DIM);
        float var = sq * (1.0f / D_DIM) - mu[r] * mu[r];
        rs[r] = rsqrtf(var + 1e-5f);
    }

    // ---- Normalize + scale/shift; stage fp32 per-wave; re-pack bf16 frags ----
    #pragma unroll
    for (int i = 0; i < 4; ++i) {
        int col = w * 64 + i * 16 + mn;
        float g = lw4[col], bb = lb4[col];
        #pragma unroll
        for (int r = 0; r < 4; ++r) {
            float x = (acc[i][r] - mu[r]) * rs[r] * g + bb;
            xs[w][q * 4 + r][i * 16 + mn] = x;
        }
    }
    __syncthreads();

    #pragma unroll
    for (int it = 0; it < 2; ++it) {
        int idx = it * 64 + lane;
        int m = idx & 15, kbl = idx >> 4;  // kbl in [0,8)
        const float* src = &xs[w][m][kbl * 8];
        float4 s0 = *(const float4*)src;
        float4 s1 = *(const float4*)(src + 4);
        uint4 u;
        u.x = f2bf(s0.x) | (f2bf(s0.y) << 16);
        u.y = f2bf(s0.z) | (f2bf(s0.w) << 16);
        u.z = f2bf(s1.x) | (f2bf(s1.y) << 16);
        u.w = f2bf(s1.z) | (f2bf(s1.w) << 16);
        lfr[w * 8 + kbl][m] = u;
    }
    __syncthreads();

    // ---- G2: out = LN4(x) @ wp + bp ----
    f32x4 acc2[4] = {{0.f,0.f,0.f,0.f},{0.f,0.f,0.f,0.f},{0.f,0.f,0.f,0.f},{0.f,0.f,0.f,0.f}};
    for (int kw = 0; kw < 16; ++kw) {
        short8 a = *(const short8*)&lfr[kw * 4 + q][mn];
        #pragma unroll
        for (int i = 0; i < 4; ++i) {
            int nt = w * 4 + i;
            short8 b = *(const short8*)(wfp + ((size_t)nt * 64 + kw * 4 + q) * 16 + mn);
            acc2[i] = __builtin_amdgcn_mfma_f32_16x16x32_bf16(a, b, acc2[i], 0, 0, 0);
        }
    }
    #pragma unroll
    for (int i = 0; i < 4; ++i) {
        int col = (w * 4 + i) * 16 + mn;
        float bv = dload(bp, col, f);
        #pragma unroll
        for (int r = 0; r < 4; ++r)
            Y[(size_t)(rt * 16 + q * 4 + r) * D_DIM + col] = acc2[i][r] + bv;
    }
}

extern "C" void kernel_launch(void* const* d_in, const int* in_sizes, int n_in,
                              void* d_out, int out_size, void* d_ws, size_t ws_size,
                              hipStream_t stream) {
    const void* model_embed = d_in[0];
    const void* ctx_key     = d_in[1];
    const void* ctx_val     = d_in[2];
    const void* ln1w = d_in[3];  const void* ln1b = d_in[4];
    const void* ln2w = d_in[5];  const void* ln2b = d_in[6];
    const void* ln3w = d_in[7];  const void* ln3b = d_in[8];
    const void* ln4w = d_in[9];  const void* ln4b = d_in[10];
    const void* wq = d_in[11];   const void* bq = d_in[12];
    const void* wk = d_in[13];   const void* bk = d_in[14];
    const void* wv = d_in[15];   const void* bv = d_in[16];
    const void* wo = d_in[17];   const void* bo = d_in[18];
    const void* wp = d_in[19];   const void* bp = d_in[20];

    int*   flagp = (int*)d_ws;
    float* ws    = (float*)d_ws + 16;
    float* o1    = ws;                         // 524288 fl (oAf lives here)
    float* qTf   = o1 + 524288;                // qf   262144 fl (1 MB)
    float* kTf   = qTf + 262144;               // kf  2097152 fl (8 MB)
    float* Aqf   = kTf + 2097152;              // Aq   262144 fl
    float* Akf   = Aqf + 262144;               // Ak  2097152 fl
    float* Avf   = Akf + 2097152;              // Av   524288 fl
    float* vff   = Avf + 524288;               // vf   524288 fl
    float* wfr   = vff + 524288;               // 655360 fl (5 W-frags)

    uint4* qf  = (uint4*)qTf;
    uint4* kf  = (uint4*)kTf;
    uint4* Aq  = (uint4*)Aqf;
    uint4* Ak  = (uint4*)Akf;
    uint4* Av  = (uint4*)Avf;
    uint4* vf  = (uint4*)vff;
    uint4* oAf = (uint4*)o1;
    uint4* wfq = (uint4*)wfr;
    uint4* wfk = wfq + 32768;
    uint4* wfv = wfk + 32768;
    uint4* wfo = wfv + 32768;
    uint4* wfp = wfo + 32768;

    pack_all_kernel<<<1024, 256, 0, stream>>>(model_embed, ln1w, ln1b,
                                              ctx_key, ln2w, ln2b,
                                              ctx_val, ln3w, ln3b,
                                              Aq, Ak, Av,
                                              wq, wk, wv, wo, wp,
                                              wfq, wfk, wfv, wfo, wfp, flagp);

    gemm_qkv_kernel<<<1408, 256, 0, stream>>>(Aq, Ak, Av, wfq, wfk, wfv,
                                              bq, bk, bv, qf, kf, vf, flagp);

    attn_fused_kernel<<<512, 512, 0, stream>>>(qf, kf, vf, oAf);

    tail2_kernel<<<64, 512, 0, stream>>>(oAf, wfo, wfp, bo, bp,
                                         ln4w, ln4b, (float*)d_out, flagp);

    (void)ws_size;
}

// Round 9
// 170.704 us; speedup vs baseline: 1.0911x; 1.0288x over previous
//
#include <hip/hip_runtime.h>
#include <hip/hip_bf16.h>

using bf16 = __hip_bfloat16;

#define D_DIM 512
#define C_DIM 2048
#define U_DIM 4
#define DK 64

typedef __attribute__((ext_vector_type(8))) short short8;
typedef __attribute__((ext_vector_type(8))) unsigned short ushort8;
typedef __attribute__((ext_vector_type(4))) float f32x4;

__device__ __forceinline__ float dload(const void* p, size_t i, int f) {
    return f ? ((const float*)p)[i] : __bfloat162float(((const bf16*)p)[i]);
}
__device__ __forceinline__ unsigned f2bf(float x) {
    bf16 b = __float2bfloat16(x);
    return (unsigned)*(unsigned short*)&b;
}
__device__ __forceinline__ float bf2f(unsigned short us) {
    unsigned u = ((unsigned)us) << 16;
    return __builtin_bit_cast(float, u);
}

// ---------------------------------------------------------------------------
// Per-block dtype detect (16 KB of model_embed viewed as bf16; L2-hot).
// ---------------------------------------------------------------------------
__device__ __forceinline__ int block_detect(const void* __restrict__ x) {
    __shared__ int sred[4];
    const bf16* xb = (const bf16*)x;
    int tid = threadIdx.x;
    int cnt = 0;
    #pragma unroll
    for (int i = 0; i < 4; ++i) {
        ushort8 a = *(const ushort8*)(xb + (size_t)(i * 256 + tid) * 8);
        #pragma unroll
        for (int j = 0; j < 8; ++j) {
            float v = fabsf(bf2f(a[j]));
            if (!(v <= 100.0f)) cnt++;
        }
    }
    #pragma unroll
    for (int o = 32; o > 0; o >>= 1) cnt += __shfl_down(cnt, o);
    if ((tid & 63) == 0) sred[tid >> 6] = cnt;
    __syncthreads();
    int c = sred[0] + sred[1] + sred[2] + sred[3];
    return (c > 400) ? 1 : 0;
}

// ---------------------------------------------------------------------------
// A-fragment pack body (dtype compile-time; all loads vectorized).
// ---------------------------------------------------------------------------
template <bool LN, bool XF, bool WF>
__device__ __forceinline__ void pack_a_body(const void* __restrict__ X,
                                            const void* __restrict__ lnw,
                                            const void* __restrict__ lnb,
                                            uint4* __restrict__ Af, int tt) {
    int m = threadIdx.x >> 4;
    int kbL = threadIdx.x & 15;
    int row = tt * 16 + m;
    float v[32];
    float s = 0.0f, ss = 0.0f;
    #pragma unroll
    for (int i = 0; i < 4; ++i) {
        int k0 = (kbL + i * 16) * 8;
        if constexpr (XF) {
            const float4* p = (const float4*)((const float*)X + (size_t)row * D_DIM + k0);
            float4 a = p[0], b = p[1];
            v[i*8+0] = a.x; v[i*8+1] = a.y; v[i*8+2] = a.z; v[i*8+3] = a.w;
            v[i*8+4] = b.x; v[i*8+5] = b.y; v[i*8+6] = b.z; v[i*8+7] = b.w;
        } else {
            ushort8 a = *(const ushort8*)((const bf16*)X + (size_t)row * D_DIM + k0);
            #pragma unroll
            for (int j = 0; j < 8; ++j) v[i*8+j] = bf2f(a[j]);
        }
        #pragma unroll
        for (int j = 0; j < 8; ++j) { float x = v[i*8+j]; s += x; ss += x * x; }
    }
    float mu = 0.0f, rs = 1.0f;
    if (LN) {
        #pragma unroll
        for (int o = 1; o < 16; o <<= 1) { s += __shfl_xor(s, o); ss += __shfl_xor(ss, o); }
        mu = s * (1.0f / D_DIM);
        float var = ss * (1.0f / D_DIM) - mu * mu;
        rs = rsqrtf(var + 1e-5f);
    }
    #pragma unroll
    for (int i = 0; i < 4; ++i) {
        int kb = kbL + i * 16;
        int k0 = kb * 8;
        float lw[8], lb[8];
        if (LN) {
            if constexpr (WF) {
                const float4* pw = (const float4*)((const float*)lnw + k0);
                const float4* pb = (const float4*)((const float*)lnb + k0);
                float4 w0 = pw[0], w1 = pw[1], b0 = pb[0], b1 = pb[1];
                lw[0]=w0.x; lw[1]=w0.y; lw[2]=w0.z; lw[3]=w0.w;
                lw[4]=w1.x; lw[5]=w1.y; lw[6]=w1.z; lw[7]=w1.w;
                lb[0]=b0.x; lb[1]=b0.y; lb[2]=b0.z; lb[3]=b0.w;
                lb[4]=b1.x; lb[5]=b1.y; lb[6]=b1.z; lb[7]=b1.w;
            } else {
                ushort8 w8 = *(const ushort8*)((const bf16*)lnw + k0);
                ushort8 b8 = *(const ushort8*)((const bf16*)lnb + k0);
                #pragma unroll
                for (int j = 0; j < 8; ++j) { lw[j] = bf2f(w8[j]); lb[j] = bf2f(b8[j]); }
            }
        }
        unsigned pk[4];
        #pragma unroll
        for (int jp = 0; jp < 4; ++jp) {
            float v0 = v[i * 8 + jp * 2];
            float v1 = v[i * 8 + jp * 2 + 1];
            if (LN) {
                v0 = (v0 - mu) * rs * lw[jp * 2] + lb[jp * 2];
                v1 = (v1 - mu) * rs * lw[jp * 2 + 1] + lb[jp * 2 + 1];
            }
            pk[jp] = f2bf(v0) | (f2bf(v1) << 16);
        }
        uint4 wv = {pk[0], pk[1], pk[2], pk[3]};
        Af[((size_t)tt * 64 + kb) * 16 + m] = wv;
    }
}

// ---------------------------------------------------------------------------
// Weight pack body (one 64x64 tile into bf16 B-fragments), dtype templated.
// ---------------------------------------------------------------------------
template <bool WF>
__device__ __forceinline__ void pack_w_body(const void* __restrict__ W,
                                            uint4* __restrict__ Bf, int b,
                                            float (*t)[65]) {
    int n0 = (b & 7) * 64, k0 = (b >> 3) * 64;
    int tid = threadIdx.x;
    if constexpr (WF) {
        #pragma unroll
        for (int i = 0; i < 4; ++i) {
            int e = i * 256 + tid;            // vec4 index in [0,1024)
            int r = e >> 4, c = (e & 15) * 4;
            float4 a = *(const float4*)((const float*)W + (size_t)(k0 + r) * D_DIM + n0 + c);
            t[r][c] = a.x; t[r][c+1] = a.y; t[r][c+2] = a.z; t[r][c+3] = a.w;
        }
    } else {
        #pragma unroll
        for (int i = 0; i < 2; ++i) {
            int e = i * 256 + tid;            // vec8 index in [0,512)
            int r = e >> 3, c = (e & 7) * 8;
            ushort8 a = *(const ushort8*)((const bf16*)W + (size_t)(k0 + r) * D_DIM + n0 + c);
            #pragma unroll
            for (int j = 0; j < 8; ++j) t[r][c + j] = bf2f(a[j]);
        }
    }
    __syncthreads();
    #pragma unroll
    for (int i = 0; i < 2; ++i) {
        int e = i * 256 + tid;
        int nl = e & 63, kbl = e >> 6;
        unsigned pk[4];
        #pragma unroll
        for (int jp = 0; jp < 4; ++jp)
            pk[jp] = f2bf(t[kbl * 8 + jp * 2][nl]) | (f2bf(t[kbl * 8 + jp * 2 + 1][nl]) << 16);
        uint4 wv = {pk[0], pk[1], pk[2], pk[3]};
        int n = n0 + nl;
        Bf[(((size_t)(n >> 4)) * 64 + (k0 / 8 + kbl)) * 16 + (n & 15)] = wv;
    }
}

// ---------------------------------------------------------------------------
// FUSED pack: [0,64) me->Aq, [64,576) ck->Ak, [576,704) cv->Av,
// [704,1024) 5 weights -> B-fragments.
// ---------------------------------------------------------------------------
__global__ __launch_bounds__(256, 1)
void pack_all_kernel(const void* __restrict__ me, const void* __restrict__ l1w, const void* __restrict__ l1b,
                     const void* __restrict__ ck, const void* __restrict__ l2w, const void* __restrict__ l2b,
                     const void* __restrict__ cv, const void* __restrict__ l3w, const void* __restrict__ l3b,
                     uint4* __restrict__ Aq, uint4* __restrict__ Ak, uint4* __restrict__ Av,
                     const void* W0, const void* W1, const void* W2,
                     const void* W3, const void* W4,
                     uint4* B0, uint4* B1, uint4* B2, uint4* B3, uint4* B4,
                     int* __restrict__ flagp) {
    __shared__ float t[64][65];
    int f = block_detect(me);
    if (blockIdx.x == 0 && threadIdx.x == 0) *flagp = f;
    int b = blockIdx.x;
    const void* Ws[5] = {W0, W1, W2, W3, W4};
    uint4* Bs[5] = {B0, B1, B2, B3, B4};
    if (f) {
        if (b < 64)       pack_a_body<true, true, true>(me, l1w, l1b, Aq, b);
        else if (b < 576) pack_a_body<true, true, true>(ck, l2w, l2b, Ak, b - 64);
        else if (b < 704) pack_a_body<true, true, true>(cv, l3w, l3b, Av, b - 576);
        else { int c = b - 704; pack_w_body<true>(Ws[c >> 6], Bs[c >> 6], c & 63, t); }
    } else {
        if (b < 64)       pack_a_body<true, false, false>(me, l1w, l1b, Aq, b);
        else if (b < 576) pack_a_body<true, false, false>(ck, l2w, l2b, Ak, b - 64);
        else if (b < 704) pack_a_body<true, false, false>(cv, l3w, l3b, Av, b - 576);
        else { int c = b - 704; pack_w_body<false>(Ws[c >> 6], Bs[c >> 6], c & 63, t); }
    }
}

// ---------------------------------------------------------------------------
// Fragment MFMA GEMM body v2: B-tile LDS double-buffer (R7, confirmed +) AND
// TWO A-row-tiles per block (by0, by0+1) against the SAME staged B quarter:
// halves B L2 traffic again, halves block count, and doubles the MFMA cover
// (32/wave) over each early-issued stage. Epilogue runs twice (barrier
// between) with the existing per-OUT logic. Math bit-identical.
// ---------------------------------------------------------------------------
template <int OUT>
__device__ __forceinline__ void mfma_gemm_body(const uint4* __restrict__ Af,
                                               const uint4* __restrict__ Bf,
                                               const void* __restrict__ bias,
                                               uint4* __restrict__ Fout, int Rtt,
                                               int f, int bx, int by0,
                                               float (*t)[65],
                                               uint4 (*bbuf)[1024]) {
    int tid = threadIdx.x;
    int w = tid >> 6, lane = tid & 63;
    int q = lane >> 4, mn = lane & 15;
    int nt0 = bx * 4;

    // Prologue: stage kw-quarter 0 (kw 0..3) into bbuf[0].
    uint4 stg[4];
    #pragma unroll
    for (int j = 0; j < 4; ++j) {
        int e = j * 256 + tid;
        int emn = e & 15, i = (e >> 4) & 3, kq = e >> 6;
        stg[j] = Bf[(((size_t)(nt0 + i)) * 64 + kq) * 16 + emn];
    }
    #pragma unroll
    for (int j = 0; j < 4; ++j) bbuf[0][j * 256 + tid] = stg[j];
    __syncthreads();

    f32x4 acc[2][4];
    #pragma unroll
    for (int j2 = 0; j2 < 2; ++j2)
        #pragma unroll
        for (int i = 0; i < 4; ++i) acc[j2][i] = {0.f, 0.f, 0.f, 0.f};

    #pragma unroll
    for (int p = 0; p < 4; ++p) {
        const int cur = p & 1;
        if (p < 3) {   // issue next-quarter loads early (latency under MFMAs)
            #pragma unroll
            for (int j = 0; j < 4; ++j) {
                int e = j * 256 + tid;
                int emn = e & 15, i = (e >> 4) & 3, kq = e >> 6;
                stg[j] = Bf[(((size_t)(nt0 + i)) * 64 + (p + 1) * 16 + kq) * 16 + emn];
            }
        }
        #pragma unroll
        for (int kwl = 0; kwl < 4; ++kwl) {
            int kw = p * 4 + kwl;
            #pragma unroll
            for (int j2 = 0; j2 < 2; ++j2) {
                int mt = (by0 + j2) * 4 + w;
                short8 a = *(const short8*)(Af + ((size_t)mt * 64 + kw * 4 + q) * 16 + mn);
                #pragma unroll
                for (int i = 0; i < 4; ++i) {
                    short8 b = *(const short8*)&bbuf[cur][((kwl * 4 + q) * 4 + i) * 16 + mn];
                    acc[j2][i] = __builtin_amdgcn_mfma_f32_16x16x32_bf16(a, b, acc[j2][i], 0, 0, 0);
                }
            }
        }
        if (p < 3) {   // write-late into the other buffer, then barrier
            #pragma unroll
            for (int j = 0; j < 4; ++j) bbuf[cur ^ 1][j * 256 + tid] = stg[j];
            __syncthreads();
        }
    }

    // Epilogue, run once per A-row-tile (t reused; barrier between).
    #pragma unroll
    for (int j2 = 0; j2 < 2; ++j2) {
        int by = by0 + j2;
        if (j2 == 1) __syncthreads();   // all reads of t from j2=0 complete
        #pragma unroll
        for (int i = 0; i < 4; ++i) {
            float bv = dload(bias, (nt0 + i) * 16 + mn, f);
            #pragma unroll
            for (int r = 0; r < 4; ++r)
                t[w * 16 + q * 4 + r][i * 16 + mn] = acc[j2][i][r] + bv;
        }
        __syncthreads();
        int h = bx;
        if constexpr (OUT == 1) {
            #pragma unroll
            for (int e0 = 0; e0 < 2; ++e0) {
                int e = e0 * 256 + threadIdx.x;
                int m = e & 15, kb = (e >> 4) & 7, ttl = e >> 7;
                const float* src = &t[ttl * 16 + m][kb * 8];
                uint4 wv;
                wv.x = f2bf(src[0]) | (f2bf(src[1]) << 16);
                wv.y = f2bf(src[2]) | (f2bf(src[3]) << 16);
                wv.z = f2bf(src[4]) | (f2bf(src[5]) << 16);
                wv.w = f2bf(src[6]) | (f2bf(src[7]) << 16);
                Fout[(((size_t)h * Rtt + by * 4 + ttl) * 8 + kb) * 16 + m] = wv;
            }
        } else if constexpr (OUT == 2) {
            #pragma unroll
            for (int e0 = 0; e0 < 2; ++e0) {
                int e = e0 * 256 + threadIdx.x;
                int lane2 = e & 63, nt = (e >> 6) & 3, ctl = e >> 8;
                int nm2 = lane2 & 15, q2 = lane2 >> 4;
                int col = nt * 16 + nm2;
                int rb = ctl * 32 + q2 * 8;
                uint4 wv;
                wv.x = f2bf(t[rb + 0][col]) | (f2bf(t[rb + 1][col]) << 16);
                wv.y = f2bf(t[rb + 2][col]) | (f2bf(t[rb + 3][col]) << 16);
                wv.z = f2bf(t[rb + 4][col]) | (f2bf(t[rb + 5][col]) << 16);
                wv.w = f2bf(t[rb + 6][col]) | (f2bf(t[rb + 7][col]) << 16);
                Fout[(((size_t)h * 64 + by * 2 + ctl) * 4 + nt) * 64 + lane2] = wv;
            }
        } else {
            #pragma unroll
            for (int e0 = 0; e0 < 2; ++e0) {
                int e = e0 * 256 + threadIdx.x;
                int m2 = e & 15, kb = (e >> 4) & 7, u = e >> 7;
                const float* src = &t[m2 * 4 + u][kb * 8];
                uint4 wv;
                wv.x = f2bf(src[0]) | (f2bf(src[1]) << 16);
                wv.y = f2bf(src[2]) | (f2bf(src[3]) << 16);
                wv.z = f2bf(src[4]) | (f2bf(src[5]) << 16);
                wv.w = f2bf(src[6]) | (f2bf(src[7]) << 16);
                int nt = by * 4 + u;
                Fout[(((size_t)h * 512 + nt) * 8 + kb) * 16 + m2] = wv;
            }
        }
    }
}

// ---------------------------------------------------------------------------
// FUSED q/k/v projection GEMMs — paired A-row-tiles, 704 blocks:
// [0,512): K (bx = b>>6, by0 = (b&63)*2); [512,640): V; [640,704): Q.
// Pair-sharing blocks sit at stride 64/16/8 (≡0 mod 8 → same XCD for K).
// ---------------------------------------------------------------------------
__global__ __launch_bounds__(256, 2)
void gemm_qkv_kernel(const uint4* __restrict__ Aq, const uint4* __restrict__ Ak,
                     const uint4* __restrict__ Av,
                     const uint4* __restrict__ wfq, const uint4* __restrict__ wfk,
                     const uint4* __restrict__ wfv,
                     const void* __restrict__ bq, const void* __restrict__ bk,
                     const void* __restrict__ bv,
                     uint4* __restrict__ qf, uint4* __restrict__ kf,
                     uint4* __restrict__ vf,
                     const int* __restrict__ flagp) {
    __shared__ float t[64][65];
    __shared__ uint4 bbuf[2][1024];      // 2 x 16 KB B-quarter double-buffer
    int f = *flagp;
    int b = blockIdx.x;
    if (b < 512) {
        mfma_gemm_body<3>(Ak, wfk, bk, kf, 512, f, b >> 6, (b & 63) * 2, t, bbuf);
    } else if (b < 640) {
        int c = b - 512;
        mfma_gemm_body<2>(Av, wfv, bv, vf, 0, f, c >> 4, (c & 15) * 2, t, bbuf);
    } else {
        int c = b - 640;
        mfma_gemm_body<1>(Aq, wfq, bq, qf, 64, f, c >> 3, (c & 7) * 2, t, bbuf);
    }
}

// ---------------------------------------------------------------------------
// FUSED MFMA flash attention v3 — IN-BLOCK c-split merge (best measured).
// ---------------------------------------------------------------------------
__global__ __launch_bounds__(512, 1)
void attn_fused_kernel(const uint4* __restrict__ qf, const uint4* __restrict__ kf,
                       const uint4* __restrict__ vf, uint4* __restrict__ oAf) {
    __shared__ float sp[8][16][36];      // per-wave P staging (18.4 KB)
    __shared__ float opar[8][16][64];    // per-wave O partials  (32 KB)
    __shared__ float mpar[8][16];        // per-wave row max
    __shared__ float lpar[8][16];        // per-wave row sum
    int tid = threadIdx.x;
    int w = tid >> 6, lane = tid & 63;
    int q = lane >> 4, nm = lane & 15;
    int b = blockIdx.x;
    int h = b & 7;               // XCD selector
    int rt = b >> 3;             // 16-row q tile
    int s = w;                   // wave = c-split chunk

    short8 a0 = *(const short8*)(qf + (((size_t)h * 64 + rt) * 8 + q) * 16 + nm);
    short8 a1 = *(const short8*)(qf + (((size_t)h * 64 + rt) * 8 + 4 + q) * 16 + nm);

    // Phase 1: scores for 8 super-tiles of this wave's chunk, MaxSim over u.
    f32x4 sc[8][2];
    #pragma unroll
    for (int st = 0; st < 8; ++st) {
        #pragma unroll
        for (int hh = 0; hh < 2; ++hh) {
            int ct16 = (s * 8 + st) * 2 + hh;
            f32x4 scv = {-1e30f, -1e30f, -1e30f, -1e30f};
            __builtin_amdgcn_s_setprio(1);
            #pragma unroll
            for (int u = 0; u < 4; ++u) {
                int nt = ct16 * 4 + u;
                short8 b0 = *(const short8*)(kf + (((size_t)h * 512 + nt) * 8 + q) * 16 + nm);
                short8 b1 = *(const short8*)(kf + (((size_t)h * 512 + nt) * 8 + 4 + q) * 16 + nm);
                f32x4 acc = {0.0f, 0.0f, 0.0f, 0.0f};
                acc = __builtin_amdgcn_mfma_f32_16x16x32_bf16(a0, b0, acc, 0, 0, 0);
                acc = __builtin_amdgcn_mfma_f32_16x16x32_bf16(a1, b1, acc, 0, 0, 0);
                #pragma unroll
                for (int r = 0; r < 4; ++r) scv[r] = fmaxf(scv[r], acc[r]);
            }
            __builtin_amdgcn_s_setprio(0);
            #pragma unroll
            for (int r = 0; r < 4; ++r) sc[st][hh][r] = scv[r] * 0.125f;  // 1/sqrt(dk)
        }
    }

    // Phase 2: chunk-local max per query row.
    float mrow[4], lrow[4];
    #pragma unroll
    for (int r = 0; r < 4; ++r) {
        float m = sc[0][0][r];
        #pragma unroll
        for (int st = 0; st < 8; ++st) {
            m = fmaxf(m, sc[st][0][r]);
            m = fmaxf(m, sc[st][1][r]);
        }
        m = fmaxf(m, __shfl_xor(m, 1));
        m = fmaxf(m, __shfl_xor(m, 2));
        m = fmaxf(m, __shfl_xor(m, 4));
        m = fmaxf(m, __shfl_xor(m, 8));
        mrow[r] = m;
        lrow[r] = 0.0f;
    }

    // Phase 3: exp -> P-frag via per-wave LDS -> PV MFMAs.
    f32x4 acc_o[4] = {{0.f,0.f,0.f,0.f},{0.f,0.f,0.f,0.f},{0.f,0.f,0.f,0.f},{0.f,0.f,0.f,0.f}};
    #pragma unroll
    for (int st = 0; st < 8; ++st) {
        #pragma unroll
        for (int r = 0; r < 4; ++r) {
            float p0 = __expf(sc[st][0][r] - mrow[r]);
            float p1 = __expf(sc[st][1][r] - mrow[r]);
            sp[w][q * 4 + r][nm] = p0;
            sp[w][q * 4 + r][16 + nm] = p1;
            lrow[r] += p0 + p1;
        }
        float4 pa0 = *(const float4*)&sp[w][nm][q * 8];
        float4 pa1 = *(const float4*)&sp[w][nm][q * 8 + 4];
        uint4 av;
        av.x = f2bf(pa0.x) | (f2bf(pa0.y) << 16);
        av.y = f2bf(pa0.z) | (f2bf(pa0.w) << 16);
        av.z = f2bf(pa1.x) | (f2bf(pa1.y) << 16);
        av.w = f2bf(pa1.z) | (f2bf(pa1.w) << 16);
        short8 ap = *(short8*)&av;
        int ct32 = s * 8 + st;
        __builtin_amdgcn_s_setprio(1);
        #pragma unroll
        for (int nt2 = 0; nt2 < 4; ++nt2) {
            short8 bv = *(const short8*)(vf + (((size_t)h * 64 + ct32) * 4 + nt2) * 64 + lane);
            acc_o[nt2] = __builtin_amdgcn_mfma_f32_16x16x32_bf16(ap, bv, acc_o[nt2], 0, 0, 0);
        }
        __builtin_amdgcn_s_setprio(0);
    }

    // Chunk-local row-sum reduction.
    #pragma unroll
    for (int r = 0; r < 4; ++r) {
        float ps = lrow[r];
        ps += __shfl_xor(ps, 1);
        ps += __shfl_xor(ps, 2);
        ps += __shfl_xor(ps, 4);
        ps += __shfl_xor(ps, 8);
        lrow[r] = ps;
    }

    // Stage partials to LDS.
    #pragma unroll
    for (int nt2 = 0; nt2 < 4; ++nt2)
        #pragma unroll
        for (int r = 0; r < 4; ++r)
            opar[w][q * 4 + r][nt2 * 16 + nm] = acc_o[nt2][r];
    if (nm == 0) {
        #pragma unroll
        for (int r = 0; r < 4; ++r) {
            mpar[w][q * 4 + r] = mrow[r];
            lpar[w][q * 4 + r] = lrow[r];
        }
    }
    __syncthreads();

    // In-block merge of the 8 c-chunk partials -> wo-GEMM A-frags.
    if (tid < 128) {
        int row = tid & 15, dg = tid >> 4;   // dg in [0,8): 8-col group
        float M = -1e30f;
        #pragma unroll
        for (int ss = 0; ss < 8; ++ss) M = fmaxf(M, mpar[ss][row]);
        float L = 0.0f;
        float o[8] = {0.f,0.f,0.f,0.f,0.f,0.f,0.f,0.f};
        #pragma unroll
        for (int ss = 0; ss < 8; ++ss) {
            float e = __expf(mpar[ss][row] - M);
            L += lpar[ss][row] * e;
            const float* po = &opar[ss][row][dg * 8];
            #pragma unroll
            for (int j = 0; j < 8; ++j) o[j] += po[j] * e;
        }
        float inv = 1.0f / L;
        uint4 u;
        u.x = f2bf(o[0] * inv) | (f2bf(o[1] * inv) << 16);
        u.y = f2bf(o[2] * inv) | (f2bf(o[3] * inv) << 16);
        u.z = f2bf(o[4] * inv) | (f2bf(o[5] * inv) << 16);
        u.w = f2bf(o[6] * inv) | (f2bf(o[7] * inv) << 16);
        int kb = h * 8 + dg;
        oAf[((size_t)rt * 64 + kb) * 16 + row] = u;
    }
}

// ---------------------------------------------------------------------------
// FUSED TAIL v2 (best measured): wo-GEMM -> LN4 -> wp-GEMM.
// 64 blocks x 512 threads.
// ---------------------------------------------------------------------------
__global__ __launch_bounds__(512, 1)
void tail2_kernel(const uint4* __restrict__ oAf,
                  const uint4* __restrict__ wfo, const uint4* __restrict__ wfp,
                  const void* __restrict__ bo, const void* __restrict__ bp,
                  const void* __restrict__ ln4w, const void* __restrict__ ln4b,
                  float* __restrict__ Y, const int* __restrict__ flagp) {
    __shared__ uint4 lfr[64][16];          // LN4(x) A-frags (16 KB)
    __shared__ float xs[8][16][68];        // per-wave fp32 x staging (34.8 KB)
    __shared__ float lw4[512], lb4[512];   // ln4 params (4 KB)
    __shared__ float sred[8][16][2];       // per-wave row (sum, sumsq) (1 KB)
    int f = *flagp;
    int tid = threadIdx.x;
    int rt = blockIdx.x;                   // rows rt*16 .. rt*16+16
    if (tid < 512) { lw4[tid] = dload(ln4w, tid, f); lb4[tid] = dload(ln4b, tid, f); }

    int w = tid >> 6, lane = tid & 63;
    int q = lane >> 4, mn = lane & 15;

    // ---- G1: x = O @ wo + bo; wave w -> nt = w*4+i ----
    f32x4 acc[4] = {{0.f,0.f,0.f,0.f},{0.f,0.f,0.f,0.f},{0.f,0.f,0.f,0.f},{0.f,0.f,0.f,0.f}};
    for (int kw = 0; kw < 16; ++kw) {
        short8 a = *(const short8*)(oAf + ((size_t)rt * 64 + kw * 4 + q) * 16 + mn);
        #pragma unroll
        for (int i = 0; i < 4; ++i) {
            int nt = w * 4 + i;
            short8 b = *(const short8*)(wfo + ((size_t)nt * 64 + kw * 4 + q) * 16 + mn);
            acc[i] = __builtin_amdgcn_mfma_f32_16x16x32_bf16(a, b, acc[i], 0, 0, 0);
        }
    }
    #pragma unroll
    for (int i = 0; i < 4; ++i) {
        float bv = dload(bo, (w * 4 + i) * 16 + mn, f);
        #pragma unroll
        for (int r = 0; r < 4; ++r) acc[i][r] += bv;
    }

    // ---- LN4 stats: in-lane over 4 nt, shfl over 16 mn, LDS over 8 waves ----
    {
        float ps[4], pq[4];
        #pragma unroll
        for (int r = 0; r < 4; ++r) {
            float s = 0.f, sq = 0.f;
            #pragma unroll
            for (int i = 0; i < 4; ++i) { float x = acc[i][r]; s += x; sq += x * x; }
            #pragma unroll
            for (int o = 1; o < 16; o <<= 1) { s += __shfl_xor(s, o); sq += __shfl_xor(sq, o); }
            ps[r] = s; pq[r] = sq;
        }
        if (mn == 0) {
            #pragma unroll
            for (int r = 0; r < 4; ++r) { sred[w][q*4+r][0] = ps[r]; sred[w][q*4+r][1] = pq[r]; }
        }
    }
    __syncthreads();

    float mu[4], rs[4];
    #pragma unroll
    for (int r = 0; r < 4; ++r) {
        int rr = q * 4 + r;
        float s = 0.f, sq = 0.f;
        #pragma unroll
        for (int ww = 0; ww < 8; ++ww) { s += sred[ww][rr][0]; sq += sred[ww][rr][1]; }
        mu[r] = s * (1.0f / D_DIM);
        float var = sq * (1.0f / D_DIM) - mu[r] * mu[r];
        rs[r] = rsqrtf(var + 1e-5f);
    }

    // ---- Normalize + scale/shift; stage fp32 per-wave; re-pack bf16 frags ----
    #pragma unroll
    for (int i = 0; i < 4; ++i) {
        int col = w * 64 + i * 16 + mn;
        float g = lw4[col], bb = lb4[col];
        #pragma unroll
        for (int r = 0; r < 4; ++r) {
            float x = (acc[i][r] - mu[r]) * rs[r] * g + bb;
            xs[w][q * 4 + r][i * 16 + mn] = x;
        }
    }
    __syncthreads();

    #pragma unroll
    for (int it = 0; it < 2; ++it) {
        int idx = it * 64 + lane;
        int m = idx & 15, kbl = idx >> 4;  // kbl in [0,8)
        const float* src = &xs[w][m][kbl * 8];
        float4 s0 = *(const float4*)src;
        float4 s1 = *(const float4*)(src + 4);
        uint4 u;
        u.x = f2bf(s0.x) | (f2bf(s0.y) << 16);
        u.y = f2bf(s0.z) | (f2bf(s0.w) << 16);
        u.z = f2bf(s1.x) | (f2bf(s1.y) << 16);
        u.w = f2bf(s1.z) | (f2bf(s1.w) << 16);
        lfr[w * 8 + kbl][m] = u;
    }
    __syncthreads();

    // ---- G2: out = LN4(x) @ wp + bp ----
    f32x4 acc2[4] = {{0.f,0.f,0.f,0.f},{0.f,0.f,0.f,0.f},{0.f,0.f,0.f,0.f},{0.f,0.f,0.f,0.f}};
    for (int kw = 0; kw < 16; ++kw) {
        short8 a = *(const short8*)&lfr[kw * 4 + q][mn];
        #pragma unroll
        for (int i = 0; i < 4; ++i) {
            int nt = w * 4 + i;
            short8 b = *(const short8*)(wfp + ((size_t)nt * 64 + kw * 4 + q) * 16 + mn);
            acc2[i] = __builtin_amdgcn_mfma_f32_16x16x32_bf16(a, b, acc2[i], 0, 0, 0);
        }
    }
    #pragma unroll
    for (int i = 0; i < 4; ++i) {
        int col = (w * 4 + i) * 16 + mn;
        float bv = dload(bp, col, f);
        #pragma unroll
        for (int r = 0; r < 4; ++r)
            Y[(size_t)(rt * 16 + q * 4 + r) * D_DIM + col] = acc2[i][r] + bv;
    }
}

extern "C" void kernel_launch(void* const* d_in, const int* in_sizes, int n_in,
                              void* d_out, int out_size, void* d_ws, size_t ws_size,
                              hipStream_t stream) {
    const void* model_embed = d_in[0];
    const void* ctx_key     = d_in[1];
    const void* ctx_val     = d_in[2];
    const void* ln1w = d_in[3];  const void* ln1b = d_in[4];
    const void* ln2w = d_in[5];  const void* ln2b = d_in[6];
    const void* ln3w = d_in[7];  const void* ln3b = d_in[8];
    const void* ln4w = d_in[9];  const void* ln4b = d_in[10];
    const void* wq = d_in[11];   const void* bq = d_in[12];
    const void* wk = d_in[13];   const void* bk = d_in[14];
    const void* wv = d_in[15];   const void* bv = d_in[16];
    const void* wo = d_in[17];   const void* bo = d_in[18];
    const void* wp = d_in[19];   const void* bp = d_in[20];

    int*   flagp = (int*)d_ws;
    float* ws    = (float*)d_ws + 16;
    float* o1    = ws;                         // 524288 fl (oAf lives here)
    float* qTf   = o1 + 524288;                // qf   262144 fl (1 MB)
    float* kTf   = qTf + 262144;               // kf  2097152 fl (8 MB)
    float* Aqf   = kTf + 2097152;              // Aq   262144 fl
    float* Akf   = Aqf + 262144;               // Ak  2097152 fl
    float* Avf   = Akf + 2097152;              // Av   524288 fl
    float* vff   = Avf + 524288;               // vf   524288 fl
    float* wfr   = vff + 524288;               // 655360 fl (5 W-frags)

    uint4* qf  = (uint4*)qTf;
    uint4* kf  = (uint4*)kTf;
    uint4* Aq  = (uint4*)Aqf;
    uint4* Ak  = (uint4*)Akf;
    uint4* Av  = (uint4*)Avf;
    uint4* vf  = (uint4*)vff;
    uint4* oAf = (uint4*)o1;
    uint4* wfq = (uint4*)wfr;
    uint4* wfk = wfq + 32768;
    uint4* wfv = wfk + 32768;
    uint4* wfo = wfv + 32768;
    uint4* wfp = wfo + 32768;

    pack_all_kernel<<<1024, 256, 0, stream>>>(model_embed, ln1w, ln1b,
                                              ctx_key, ln2w, ln2b,
                                              ctx_val, ln3w, ln3b,
                                              Aq, Ak, Av,
                                              wq, wk, wv, wo, wp,
                                              wfq, wfk, wfv, wfo, wfp, flagp);

    gemm_qkv_kernel<<<704, 256, 0, stream>>>(Aq, Ak, Av, wfq, wfk, wfv,
                                             bq, bk, bv, qf, kf, vf, flagp);

    attn_fused_kernel<<<512, 512, 0, stream>>>(qf, kf, vf, oAf);

    tail2_kernel<<<64, 512, 0, stream>>>(oAf, wfo, wfp, bo, bp,
                                         ln4w, ln4b, (float*)d_out, flagp);

    (void)ws_size;
}